// Round 7
// baseline (651.089 us; speedup 1.0000x reference)
//
#include <hip/hip_runtime.h>
#include <hip/hip_bf16.h>

#define NEG_SLOPE 0.2f

// bf16 helpers: store with RNE, load via bit-shift (exact)
__device__ __forceinline__ unsigned short f2b(float f) {
  unsigned int u = __float_as_uint(f);
  unsigned int r = (u + 0x7FFFu + ((u >> 16) & 1u)) >> 16;
  return (unsigned short)r;
}
__device__ __forceinline__ float b2f(unsigned short v) {
  return __uint_as_float(((unsigned int)v) << 16);
}
__device__ __forceinline__ float leaky_exp(float e) {
  e = e > 0.f ? e : NEG_SLOPE * e;
  return __expf(e);
}

#define BM 64
#define BN 64
#define BK 16

// ------------------------------ layer-2 GEMM: h2b[M,64] = hact1[M,256] @ W2
__global__ __launch_bounds__(256) void k_gemm2(const float* __restrict__ A,
                                               const float* __restrict__ B,
                                               unsigned short* __restrict__ Cb,
                                               int M) {
  __shared__ __align__(16) float As[BK][BM + 4];
  __shared__ __align__(16) float Bs[BK][BN + 4];
  const int t = threadIdx.x;
  const int bm = blockIdx.x * BM;
  const int tx = t & 15, ty = t >> 4;
  float acc[4][4] = {};

  for (int k0 = 0; k0 < 256; k0 += BK) {
#pragma unroll
    for (int i = 0; i < 4; i++) {
      int idx = t + i * 256;
      int r = idx >> 4, c = idx & 15;
      int gr = bm + r;
      As[c][r] = (gr < M) ? A[(size_t)gr * 256 + k0 + c] : 0.f;
    }
#pragma unroll
    for (int i = 0; i < 4; i++) {
      int idx = t + i * 256;
      int r = idx >> 6, c = idx & 63;
      Bs[r][c] = B[(size_t)(k0 + r) * 64 + c];
    }
    __syncthreads();
#pragma unroll
    for (int kk = 0; kk < BK; kk++) {
      float4 av = *reinterpret_cast<const float4*>(&As[kk][ty * 4]);
      float4 bv = *reinterpret_cast<const float4*>(&Bs[kk][tx * 4]);
      float a[4] = {av.x, av.y, av.z, av.w};
      float b[4] = {bv.x, bv.y, bv.z, bv.w};
#pragma unroll
      for (int i = 0; i < 4; i++)
#pragma unroll
        for (int j = 0; j < 4; j++) acc[i][j] = fmaf(a[i], b[j], acc[i][j]);
    }
    __syncthreads();
  }
#pragma unroll
  for (int i = 0; i < 4; i++) {
    int gr = bm + ty * 4 + i;
    if (gr < M) {
      ushort4 o = {f2b(acc[i][0]), f2b(acc[i][1]), f2b(acc[i][2]), f2b(acc[i][3])};
      *reinterpret_cast<ushort4*>(&Cb[(size_t)gr * 64 + tx * 4]) = o;
    }
  }
}

// -------------------------------------------- per-head GEMM with fused epilog
__global__ __launch_bounds__(256) void k_gemm_head(const unsigned short* __restrict__ Ab,
                                                   const float* __restrict__ W1,
                                                   const float* __restrict__ b1,
                                                   float* __restrict__ Cout,
                                                   int M) {
  __shared__ __align__(16) float As[BK][BM + 4];
  __shared__ __align__(16) float Bs[BK][BN + 4];
  const int t = threadIdx.x;
  const int bm = blockIdx.x * BM;
  const int h = blockIdx.z;
  const int aoff = h * 128;
  const int boff = h * 64;
  const int tx = t & 15, ty = t >> 4;
  float acc[4][4] = {};

  const int ar = t >> 2;
  const int akg = (t & 3) * 4;
  const int agr = bm + ar;

  for (int k0 = 0; k0 < 128; k0 += BK) {
    ushort4 av4 = {0, 0, 0, 0};
    if (agr < M)
      av4 = *reinterpret_cast<const ushort4*>(Ab + (size_t)agr * 512 + aoff + k0 + akg);
    As[akg + 0][ar] = b2f(av4.x);
    As[akg + 1][ar] = b2f(av4.y);
    As[akg + 2][ar] = b2f(av4.z);
    As[akg + 3][ar] = b2f(av4.w);
#pragma unroll
    for (int i = 0; i < 4; i++) {
      int idx = t + i * 256;
      int r = idx >> 6, c = idx & 63;
      Bs[r][c] = W1[(size_t)(k0 + r) * 256 + boff + c];
    }
    __syncthreads();
#pragma unroll
    for (int kk = 0; kk < BK; kk++) {
      float4 av = *reinterpret_cast<const float4*>(&As[kk][ty * 4]);
      float4 bv = *reinterpret_cast<const float4*>(&Bs[kk][tx * 4]);
      float a[4] = {av.x, av.y, av.z, av.w};
      float b[4] = {bv.x, bv.y, bv.z, bv.w};
#pragma unroll
      for (int i = 0; i < 4; i++)
#pragma unroll
        for (int j = 0; j < 4; j++) acc[i][j] = fmaf(a[i], b[j], acc[i][j]);
    }
    __syncthreads();
  }
  float4 bb = *reinterpret_cast<const float4*>(b1 + boff + tx * 4);
#pragma unroll
  for (int i = 0; i < 4; i++) {
    int gr = bm + ty * 4 + i;
    if (gr < M) {
      float4 o;
      o.x = fmaxf(acc[i][0] + bb.x, 0.f);
      o.y = fmaxf(acc[i][1] + bb.y, 0.f);
      o.z = fmaxf(acc[i][2] + bb.z, 0.f);
      o.w = fmaxf(acc[i][3] + bb.w, 0.f);
      *reinterpret_cast<float4*>(&Cout[(size_t)gr * 256 + boff + tx * 4]) = o;
    }
  }
}

// ----------------------------------- project W1 @ a_src/a_dst -> va[128][8]
__global__ void k_vproj(const float* __restrict__ W1,
                        const float* __restrict__ a_src1,
                        const float* __restrict__ a_dst1,
                        float* __restrict__ va) {
  int g = blockIdx.x * 256 + threadIdx.x;
  if (g >= 1024) return;
  int k = g >> 3, j = g & 7;
  int h = j & 3;
  const float* a = (j < 4) ? a_src1 : a_dst1;
  float s = 0.f;
  for (int c = 0; c < 64; c++) s += W1[(size_t)k * 256 + h * 64 + c] * a[h * 64 + c];
  va[k * 8 + j] = s;
}

// --------------- scores from x: [N,8] = x[N,128]@va  + fused bf16 cast of x
__global__ __launch_bounds__(256) void k_scores_x(const float* __restrict__ x,
                                                  const float* __restrict__ va,
                                                  float* __restrict__ s_src,
                                                  float* __restrict__ s_dst,
                                                  unsigned short* __restrict__ xb,
                                                  int N) {
  int n = blockIdx.x * 4 + (threadIdx.x >> 6);
  if (n >= N) return;
  int lane = threadIdx.x & 63;
  float x0 = x[(size_t)n * 128 + lane];
  float x1 = x[(size_t)n * 128 + 64 + lane];
  xb[(size_t)n * 128 + lane] = f2b(x0);
  xb[(size_t)n * 128 + 64 + lane] = f2b(x1);
  float4 vs0 = *reinterpret_cast<const float4*>(va + lane * 8);
  float4 vd0 = *reinterpret_cast<const float4*>(va + lane * 8 + 4);
  float4 vs1 = *reinterpret_cast<const float4*>(va + (lane + 64) * 8);
  float4 vd1 = *reinterpret_cast<const float4*>(va + (lane + 64) * 8 + 4);
  float rs0 = x0 * vs0.x + x1 * vs1.x, rs1 = x0 * vs0.y + x1 * vs1.y;
  float rs2 = x0 * vs0.z + x1 * vs1.z, rs3 = x0 * vs0.w + x1 * vs1.w;
  float rd0 = x0 * vd0.x + x1 * vd1.x, rd1 = x0 * vd0.y + x1 * vd1.y;
  float rd2 = x0 * vd0.z + x1 * vd1.z, rd3 = x0 * vd0.w + x1 * vd1.w;
#pragma unroll
  for (int off = 32; off; off >>= 1) {
    rs0 += __shfl_xor(rs0, off, 64); rs1 += __shfl_xor(rs1, off, 64);
    rs2 += __shfl_xor(rs2, off, 64); rs3 += __shfl_xor(rs3, off, 64);
    rd0 += __shfl_xor(rd0, off, 64); rd1 += __shfl_xor(rd1, off, 64);
    rd2 += __shfl_xor(rd2, off, 64); rd3 += __shfl_xor(rd3, off, 64);
  }
  if (lane == 0) {
    float4 ss = {rs0, rs1, rs2, rs3};
    float4 dd = {rd0, rd1, rd2, rd3};
    *reinterpret_cast<float4*>(s_src + (size_t)n * 4) = ss;
    *reinterpret_cast<float4*>(s_dst + (size_t)n * 4) = dd;
  }
}

// ------------------------------------------- scores for layer 2 (bf16 input)
__global__ __launch_bounds__(256) void k_scores2(const unsigned short* __restrict__ h2b,
                                                 const float* __restrict__ a_src,
                                                 const float* __restrict__ a_dst,
                                                 float* __restrict__ s_src,
                                                 float* __restrict__ s_dst,
                                                 int N) {
  int n = blockIdx.x * 4 + (threadIdx.x >> 6);
  if (n >= N) return;
  int lane = threadIdx.x & 63;
  float hv = b2f(h2b[(size_t)n * 64 + lane]);
  float sv = hv * a_src[lane];
  float dv = hv * a_dst[lane];
#pragma unroll
  for (int off = 32; off; off >>= 1) {
    sv += __shfl_xor(sv, off, 64);
    dv += __shfl_xor(dv, off, 64);
  }
  if (lane == 0) {
    s_src[n] = sv;
    s_dst[n] = dv;
  }
}

// ----------------------------------------------- count init: 1 per node
// (slot 0 of every CSR segment is reserved for the node's self-loop)
__global__ void k_init1(int* __restrict__ count, int N) {
  int i = blockIdx.x * 256 + threadIdx.x;
  if (i < N) count[i] = 1;
}

// ------------------------- degree over real edges, 8 edges/thread (MLP)
__global__ void k_degree(const int* __restrict__ ei, int E,
                         int* __restrict__ count) {
  int base = (blockIdx.x * 256 + threadIdx.x) * 8;
  if (base >= E) return;
  const int* dsts = ei + E;
  if (base + 8 <= E && (E & 3) == 0) {
    int4 a = *reinterpret_cast<const int4*>(dsts + base);
    int4 b = *reinterpret_cast<const int4*>(dsts + base + 4);
    atomicAdd(&count[a.x], 1); atomicAdd(&count[a.y], 1);
    atomicAdd(&count[a.z], 1); atomicAdd(&count[a.w], 1);
    atomicAdd(&count[b.x], 1); atomicAdd(&count[b.y], 1);
    atomicAdd(&count[b.z], 1); atomicAdd(&count[b.w], 1);
  } else {
    for (int e = base; e < E && e < base + 8; e++) atomicAdd(&count[dsts[e]], 1);
  }
}

__global__ __launch_bounds__(1024) void k_scan(const int* __restrict__ count,
                                               int* __restrict__ row_ptr,
                                               int* __restrict__ cursor,
                                               int* __restrict__ src_sorted, int N) {
  __shared__ int warp_sums[16];
  __shared__ int carry_s;
  const int t = threadIdx.x;
  const int lane = t & 63, wid = t >> 6;
  if (t == 0) carry_s = 0;
  __syncthreads();
  for (int base = 0; base < N; base += 1024) {
    int i = base + t;
    int v = (i < N) ? count[i] : 0;
    int x = v;
#pragma unroll
    for (int off = 1; off < 64; off <<= 1) {
      int y = __shfl_up(x, off, 64);
      if (lane >= off) x += y;
    }
    if (lane == 63) warp_sums[wid] = x;
    __syncthreads();
    if (wid == 0) {
      int s = (lane < 16) ? warp_sums[lane] : 0;
#pragma unroll
      for (int off = 1; off < 16; off <<= 1) {
        int y = __shfl_up(s, off, 64);
        if (lane >= off) s += y;
      }
      if (lane < 16) warp_sums[lane] = s;
    }
    __syncthreads();
    int woff = (wid > 0) ? warp_sums[wid - 1] : 0;
    int incl = x + woff;
    int carry = carry_s;
    if (i < N) {
      int excl = carry + incl - v;
      row_ptr[i] = excl;
      cursor[i] = excl + 1;     // slot 0 reserved for self-loop
      src_sorted[excl] = i;     // self-loop placed here
    }
    __syncthreads();
    if (t == 1023) carry_s = carry + incl;
    __syncthreads();
  }
  if (t == 0) row_ptr[N] = carry_s;
}

// --------------- scatter: 8 edges/thread -> 8 atomics in flight (MLP)
__global__ void k_scatter(const int* __restrict__ ei, int E,
                          int* __restrict__ cursor,
                          int* __restrict__ src_sorted) {
  int base = (blockIdx.x * 256 + threadIdx.x) * 8;
  if (base >= E) return;
  if (base + 8 <= E && (E & 3) == 0) {
    int4 s0 = *reinterpret_cast<const int4*>(ei + base);
    int4 s1 = *reinterpret_cast<const int4*>(ei + base + 4);
    int4 d0 = *reinterpret_cast<const int4*>(ei + E + base);
    int4 d1 = *reinterpret_cast<const int4*>(ei + E + base + 4);
    int pos[8];
    pos[0] = atomicAdd(&cursor[d0.x], 1);
    pos[1] = atomicAdd(&cursor[d0.y], 1);
    pos[2] = atomicAdd(&cursor[d0.z], 1);
    pos[3] = atomicAdd(&cursor[d0.w], 1);
    pos[4] = atomicAdd(&cursor[d1.x], 1);
    pos[5] = atomicAdd(&cursor[d1.y], 1);
    pos[6] = atomicAdd(&cursor[d1.z], 1);
    pos[7] = atomicAdd(&cursor[d1.w], 1);
    src_sorted[pos[0]] = s0.x;
    src_sorted[pos[1]] = s0.y;
    src_sorted[pos[2]] = s0.z;
    src_sorted[pos[3]] = s0.w;
    src_sorted[pos[4]] = s1.x;
    src_sorted[pos[5]] = s1.y;
    src_sorted[pos[6]] = s1.z;
    src_sorted[pos[7]] = s1.w;
  } else {
    for (int e = base; e < E && e < base + 8; e++) {
      int pos = atomicAdd(&cursor[ei[E + e]], 1);
      src_sorted[pos] = ei[e];
    }
  }
}

// --------------- layer-1 edge weights in CSR order (coalesced writes)
__global__ __launch_bounds__(256) void k_w1csr(const int* __restrict__ row_ptr,
                                               const int* __restrict__ src_sorted,
                                               const float* __restrict__ s_src,
                                               const float* __restrict__ s_dst,
                                               float4* __restrict__ w1s, int N) {
  int n = blockIdx.x * 4 + (threadIdx.x >> 6);
  if (n >= N) return;
  int lane = threadIdx.x & 63;
  float4 sd = *reinterpret_cast<const float4*>(s_dst + (size_t)n * 4);
  int beg = row_ptr[n], end = row_ptr[n + 1];
  for (int p = beg + lane; p < end; p += 64) {
    int s = src_sorted[p];
    float4 ss = *reinterpret_cast<const float4*>(s_src + (size_t)s * 4);
    float4 w;
    w.x = leaky_exp(ss.x + sd.x);
    w.y = leaky_exp(ss.y + sd.y);
    w.z = leaky_exp(ss.z + sd.z);
    w.w = leaky_exp(ss.w + sd.w);
    w1s[p] = w;
  }
}

// --------------- layer-2 edge weights in CSR order
__global__ __launch_bounds__(256) void k_w2csr(const int* __restrict__ row_ptr,
                                               const int* __restrict__ src_sorted,
                                               const float* __restrict__ s2s,
                                               const float* __restrict__ s2d,
                                               float* __restrict__ w2s, int N) {
  int n = blockIdx.x * 4 + (threadIdx.x >> 6);
  if (n >= N) return;
  int lane = threadIdx.x & 63;
  float sdn = s2d[n];
  int beg = row_ptr[n], end = row_ptr[n + 1];
  for (int p = beg + lane; p < end; p += 64) {
    w2s[p] = leaky_exp(s2s[src_sorted[p]] + sdn);
  }
}

// ---------------------------- layer-1 aggregation over x (bf16), 4 heads
__global__ __launch_bounds__(256) void k_aggx(const unsigned short* __restrict__ xb,
                                              const int* __restrict__ row_ptr,
                                              const int* __restrict__ src_sorted,
                                              const float4* __restrict__ w1s,
                                              unsigned short* __restrict__ avgxb,
                                              int N) {
  int n = blockIdx.x * 4 + (threadIdx.x >> 6);
  if (n >= N) return;
  int lane = threadIdx.x & 63;
  int beg = row_ptr[n], end = row_ptr[n + 1];
  float acc[4][2] = {};
  float wsum[4] = {};
  int p = beg;
  for (; p + 4 <= end; p += 4) {
    int s[4];
    float4 w[4];
    unsigned int pk[4];
#pragma unroll
    for (int j = 0; j < 4; j++) s[j] = src_sorted[p + j];
#pragma unroll
    for (int j = 0; j < 4; j++) w[j] = w1s[p + j];
#pragma unroll
    for (int j = 0; j < 4; j++)
      pk[j] = *reinterpret_cast<const unsigned int*>(xb + (size_t)s[j] * 128 + lane * 2);
#pragma unroll
    for (int j = 0; j < 4; j++) {
      float x0 = __uint_as_float(pk[j] << 16);
      float x1 = __uint_as_float(pk[j] & 0xFFFF0000u);
      acc[0][0] = fmaf(w[j].x, x0, acc[0][0]); acc[0][1] = fmaf(w[j].x, x1, acc[0][1]);
      acc[1][0] = fmaf(w[j].y, x0, acc[1][0]); acc[1][1] = fmaf(w[j].y, x1, acc[1][1]);
      acc[2][0] = fmaf(w[j].z, x0, acc[2][0]); acc[2][1] = fmaf(w[j].z, x1, acc[2][1]);
      acc[3][0] = fmaf(w[j].w, x0, acc[3][0]); acc[3][1] = fmaf(w[j].w, x1, acc[3][1]);
      wsum[0] += w[j].x; wsum[1] += w[j].y; wsum[2] += w[j].z; wsum[3] += w[j].w;
    }
  }
  for (; p < end; p++) {
    int s = src_sorted[p];
    float4 w = w1s[p];
    unsigned int pk = *reinterpret_cast<const unsigned int*>(xb + (size_t)s * 128 + lane * 2);
    float x0 = __uint_as_float(pk << 16);
    float x1 = __uint_as_float(pk & 0xFFFF0000u);
    acc[0][0] = fmaf(w.x, x0, acc[0][0]); acc[0][1] = fmaf(w.x, x1, acc[0][1]);
    acc[1][0] = fmaf(w.y, x0, acc[1][0]); acc[1][1] = fmaf(w.y, x1, acc[1][1]);
    acc[2][0] = fmaf(w.z, x0, acc[2][0]); acc[2][1] = fmaf(w.z, x1, acc[2][1]);
    acc[3][0] = fmaf(w.w, x0, acc[3][0]); acc[3][1] = fmaf(w.w, x1, acc[3][1]);
    wsum[0] += w.x; wsum[1] += w.y; wsum[2] += w.z; wsum[3] += w.w;
  }
#pragma unroll
  for (int h = 0; h < 4; h++) {
    float inv = 1.f / (wsum[h] + 1e-16f);
    unsigned int pk = ((unsigned int)f2b(acc[h][1] * inv) << 16) | f2b(acc[h][0] * inv);
    *reinterpret_cast<unsigned int*>(avgxb + (size_t)n * 512 + h * 128 + lane * 2) = pk;
  }
}

// -------------------- layer-2 aggregation (bf16 h2) + fused relu + out head
__global__ __launch_bounds__(256) void k_agg2(const unsigned short* __restrict__ h2b,
                                              const int* __restrict__ row_ptr,
                                              const int* __restrict__ src_sorted,
                                              const float* __restrict__ w2s,
                                              const float* __restrict__ bias,
                                              const float* __restrict__ Wout,
                                              const float* __restrict__ bout,
                                              float* __restrict__ logits, int N) {
  int n = blockIdx.x * 4 + (threadIdx.x >> 6);
  if (n >= N) return;
  int lane = threadIdx.x & 63;
  int beg = row_ptr[n], end = row_ptr[n + 1];
  float acc = 0.f, wsum = 0.f;
  int p = beg;
  for (; p + 8 <= end; p += 8) {
    int s[8];
    float w[8];
    unsigned short hv[8];
#pragma unroll
    for (int j = 0; j < 8; j++) s[j] = src_sorted[p + j];
#pragma unroll
    for (int j = 0; j < 8; j++) w[j] = w2s[p + j];
#pragma unroll
    for (int j = 0; j < 8; j++) hv[j] = h2b[(size_t)s[j] * 64 + lane];
#pragma unroll
    for (int j = 0; j < 8; j++) {
      acc = fmaf(w[j], b2f(hv[j]), acc);
      wsum += w[j];
    }
  }
  for (; p < end; p++) {
    float w = w2s[p];
    acc = fmaf(w, b2f(h2b[(size_t)src_sorted[p] * 64 + lane]), acc);
    wsum += w;
  }
  float o = fmaxf(acc / (wsum + 1e-16f) + bias[lane], 0.f);
  float v = o * Wout[lane];
#pragma unroll
  for (int off = 32; off; off >>= 1) v += __shfl_xor(v, off, 64);
  if (lane == 0) logits[n] = v + bout[0];
}

extern "C" void kernel_launch(void* const* d_in, const int* in_sizes, int n_in,
                              void* d_out, int out_size, void* d_ws, size_t ws_size,
                              hipStream_t stream) {
  const float* x      = (const float*)d_in[0];
  const int*   ei     = (const int*)d_in[1];
  const float* W1     = (const float*)d_in[2];
  const float* a_src1 = (const float*)d_in[3];
  const float* a_dst1 = (const float*)d_in[4];
  const float* b1     = (const float*)d_in[5];
  const float* W2     = (const float*)d_in[6];
  const float* a_src2 = (const float*)d_in[7];
  const float* a_dst2 = (const float*)d_in[8];
  const float* b2     = (const float*)d_in[9];
  const float* Wout   = (const float*)d_in[10];
  const float* bout   = (const float*)d_in[11];
  float* logits = (float*)d_out;

  const int HC1  = in_sizes[5];           // 256
  const int F_IN = in_sizes[2] / HC1;     // 128
  const int N    = in_sizes[0] / F_IN;    // 50000
  const int E    = in_sizes[1] / 2;       // 1.6M
  const int Etot = E + N;

  char* w = (char*)d_ws;
  auto alloc = [&](size_t bytes) {
    char* p = w;
    w += (bytes + 255) & ~(size_t)255;
    return p;
  };
  // region A: xb (bf16 x); dead after k_aggx
  char* regA = alloc((size_t)N * 128 * sizeof(unsigned short));  // 12.8 MB
  unsigned short* xb = (unsigned short*)regA;
  // region B: avgxb (bf16); dead after gemm_head -> h2b at offset 0,
  // w2s at offset 25.6 MB.
  char* regB = alloc((size_t)N * 512 * sizeof(unsigned short));  // 51.2 MB
  unsigned short* avgxb = (unsigned short*)regB;
  unsigned short* h2b = (unsigned short*)regB;
  float* w2s = (float*)(regB + (size_t)N * 256 * sizeof(unsigned short));
  // region C: w1s (26.4 MB), dead before k_gemm_head writes hact1 (51.2 MB).
  char* regC = alloc((size_t)N * 256 * 4);                       // 51.2 MB
  float* hact1 = (float*)regC;
  float4* w1s = (float4*)regC;
  float* s_src1  = (float*)alloc((size_t)N * 4 * 4);
  float* s_dst1  = (float*)alloc((size_t)N * 4 * 4);
  float* s2_src  = (float*)alloc((size_t)N * 4);
  float* s2_dst  = (float*)alloc((size_t)N * 4);
  float* va      = (float*)alloc(128 * 8 * 4);
  int* count     = (int*)alloc((size_t)N * 4);
  int* cursor    = (int*)alloc((size_t)N * 4);
  int* row_ptr   = (int*)alloc((size_t)(N + 1) * 4);
  int* src_sorted= (int*)alloc((size_t)Etot * 4);

  // ---- layer 1 (h1 never materialized) ----
  k_vproj<<<4, 256, 0, stream>>>(W1, a_src1, a_dst1, va);
  k_scores_x<<<(N + 3) / 4, 256, 0, stream>>>(x, va, s_src1, s_dst1, xb, N);
  k_init1<<<(N + 255) / 256, 256, 0, stream>>>(count, N);
  k_degree<<<(E / 8 + 255) / 256, 256, 0, stream>>>(ei, E, count);
  k_scan<<<1, 1024, 0, stream>>>(count, row_ptr, cursor, src_sorted, N);
  k_scatter<<<(E / 8 + 255) / 256, 256, 0, stream>>>(ei, E, cursor, src_sorted);
  k_w1csr<<<(N + 3) / 4, 256, 0, stream>>>(row_ptr, src_sorted, s_src1, s_dst1, w1s, N);
  k_aggx<<<(N + 3) / 4, 256, 0, stream>>>(xb, row_ptr, src_sorted, w1s, avgxb, N);
  dim3 g1((N + BM - 1) / BM, 1, 4);
  k_gemm_head<<<g1, 256, 0, stream>>>(avgxb, W1, b1, hact1, N);

  // ---- layer 2 ----
  k_gemm2<<<(N + BM - 1) / BM, 256, 0, stream>>>(hact1, W2, h2b, N);
  k_scores2<<<(N + 3) / 4, 256, 0, stream>>>(h2b, a_src2, a_dst2, s2_src, s2_dst, N);
  k_w2csr<<<(N + 3) / 4, 256, 0, stream>>>(row_ptr, src_sorted, s2_src, s2_dst, w2s, N);
  k_agg2<<<(N + 3) / 4, 256, 0, stream>>>(h2b, row_ptr, src_sorted, w2s,
                                          b2, Wout, bout, logits, N);
}

// Round 8
// 595.520 us; speedup vs baseline: 1.0933x; 1.0933x over previous
//
#include <hip/hip_runtime.h>
#include <hip/hip_bf16.h>

#define NEG_SLOPE 0.2f

using bf16x8 = __attribute__((ext_vector_type(8))) short;  // 8 bf16 (4 VGPRs)
using f32x4  = __attribute__((ext_vector_type(4))) float;  // 4 fp32 acc

// bf16 helpers: store with RNE, load via bit-shift (exact)
__device__ __forceinline__ unsigned short f2b(float f) {
  unsigned int u = __float_as_uint(f);
  unsigned int r = (u + 0x7FFFu + ((u >> 16) & 1u)) >> 16;
  return (unsigned short)r;
}
__device__ __forceinline__ float b2f(unsigned short v) {
  return __uint_as_float(((unsigned int)v) << 16);
}
__device__ __forceinline__ float leaky_exp(float e) {
  e = e > 0.f ? e : NEG_SLOPE * e;
  return __expf(e);
}

// ---------------- weight prep: swizzle W into MFMA B-fragment order, hi/lo ----
// Fragment order (16x16x32, layout per m97/m92): for k-chunk kc, n-subtile t,
// lane l holds B[kc*32 + (l>>4)*8 + j][t*16 + (l&15)], j=0..7 contiguous.
// W1: [128][256] (4 heads x 64 cols).  out idx: (((h*4+kc)*4+t)*64+l)*8+j
__global__ void k_prepW1(const float* __restrict__ W1,
                         unsigned short* __restrict__ Wh,
                         unsigned short* __restrict__ Wl) {
  int g = blockIdx.x * 256 + threadIdx.x;
  if (g >= 4096) return;
  int l = g & 63, t = (g >> 6) & 3, kc = (g >> 8) & 3, h = (g >> 10) & 3;
  int n = h * 64 + t * 16 + (l & 15);
  int kbase = kc * 32 + (l >> 4) * 8;
  unsigned short hi[8], lo[8];
#pragma unroll
  for (int j = 0; j < 8; j++) {
    float v = W1[(size_t)(kbase + j) * 256 + n];
    hi[j] = f2b(v);
    lo[j] = f2b(v - b2f(hi[j]));
  }
  size_t base = ((((size_t)h * 4 + kc) * 4 + t) * 64 + l) * 8;
#pragma unroll
  for (int j = 0; j < 8; j++) { Wh[base + j] = hi[j]; Wl[base + j] = lo[j]; }
}

// W2: [256][64].  out idx: ((kc*4+t)*64+l)*8+j, kc=0..7
__global__ void k_prepW2(const float* __restrict__ W2,
                         unsigned short* __restrict__ Wh,
                         unsigned short* __restrict__ Wl) {
  int g = blockIdx.x * 256 + threadIdx.x;
  if (g >= 2048) return;
  int l = g & 63, t = (g >> 6) & 3, kc = (g >> 8) & 7;
  int n = t * 16 + (l & 15);
  int kbase = kc * 32 + (l >> 4) * 8;
  unsigned short hi[8], lo[8];
#pragma unroll
  for (int j = 0; j < 8; j++) {
    float v = W2[(size_t)(kbase + j) * 64 + n];
    hi[j] = f2b(v);
    lo[j] = f2b(v - b2f(hi[j]));
  }
  size_t base = (((size_t)kc * 4 + t) * 64 + l) * 8;
#pragma unroll
  for (int j = 0; j < 8; j++) { Wh[base + j] = hi[j]; Wl[base + j] = lo[j]; }
}

// ------------- layer-1 GEMM via MFMA: hact = relu(avgxb @ (W1h+W1l) + b1)
// A bf16 [M,512] (head-packed), per-head K=128. Wave computes 16x64 tile.
// Output stored as bf16 hi/lo pair (fp32-accurate representation).
__global__ __launch_bounds__(256) void k_gh_mfma(const unsigned short* __restrict__ Ab,
                                                 const unsigned short* __restrict__ W1h,
                                                 const unsigned short* __restrict__ W1l,
                                                 const float* __restrict__ b1,
                                                 unsigned short* __restrict__ hact_hi,
                                                 unsigned short* __restrict__ hact_lo,
                                                 int M) {
  const int w = threadIdx.x >> 6, l = threadIdx.x & 63;
  const int h = blockIdx.z;
  const int rowA = blockIdx.x * 64 + w * 16 + (l & 15);
  const int rA = rowA < M ? rowA : M - 1;
  const int kg = l >> 4;
  const unsigned short* Aptr = Ab + (size_t)rA * 512 + h * 128 + kg * 8;
  f32x4 acc[4] = {{0.f, 0.f, 0.f, 0.f}, {0.f, 0.f, 0.f, 0.f},
                  {0.f, 0.f, 0.f, 0.f}, {0.f, 0.f, 0.f, 0.f}};
#pragma unroll
  for (int kc = 0; kc < 4; kc++) {
    bf16x8 a = *reinterpret_cast<const bf16x8*>(Aptr + kc * 32);
#pragma unroll
    for (int t = 0; t < 4; t++) {
      size_t base = ((((size_t)h * 4 + kc) * 4 + t) * 64 + l) * 8;
      bf16x8 bh = *reinterpret_cast<const bf16x8*>(W1h + base);
      bf16x8 bl = *reinterpret_cast<const bf16x8*>(W1l + base);
      acc[t] = __builtin_amdgcn_mfma_f32_16x16x32_bf16(a, bh, acc[t], 0, 0, 0);
      acc[t] = __builtin_amdgcn_mfma_f32_16x16x32_bf16(a, bl, acc[t], 0, 0, 0);
    }
  }
  // D layout: col = lane&15, row = 4*(lane>>4)+reg  [m89/m91 verified]
  const int orow0 = blockIdx.x * 64 + w * 16 + (l >> 4) * 4;
  const int col16 = l & 15;
#pragma unroll
  for (int t = 0; t < 4; t++) {
    int col = h * 64 + t * 16 + col16;
    float bb = b1[col];
#pragma unroll
    for (int r = 0; r < 4; r++) {
      int row = orow0 + r;
      if (row < M) {
        float v = fmaxf(acc[t][r] + bb, 0.f);
        unsigned short hi = f2b(v);
        hact_hi[(size_t)row * 256 + col] = hi;
        hact_lo[(size_t)row * 256 + col] = f2b(v - b2f(hi));
      }
    }
  }
}

// ------------- layer-2 GEMM via MFMA: h2b = (Ah+Al) @ (W2h+W2l), K=256
// (Al@Bl term dropped: ~2^-18 relative).  Output bf16.
__global__ __launch_bounds__(256) void k_g2_mfma(const unsigned short* __restrict__ Ahi,
                                                 const unsigned short* __restrict__ Alo,
                                                 const unsigned short* __restrict__ W2h,
                                                 const unsigned short* __restrict__ W2l,
                                                 unsigned short* __restrict__ h2b,
                                                 int M) {
  const int w = threadIdx.x >> 6, l = threadIdx.x & 63;
  const int rowA = blockIdx.x * 64 + w * 16 + (l & 15);
  const int rA = rowA < M ? rowA : M - 1;
  const int kg = l >> 4;
  const unsigned short* Ah = Ahi + (size_t)rA * 256 + kg * 8;
  const unsigned short* Al = Alo + (size_t)rA * 256 + kg * 8;
  f32x4 acc[4] = {{0.f, 0.f, 0.f, 0.f}, {0.f, 0.f, 0.f, 0.f},
                  {0.f, 0.f, 0.f, 0.f}, {0.f, 0.f, 0.f, 0.f}};
#pragma unroll
  for (int kc = 0; kc < 8; kc++) {
    bf16x8 ah = *reinterpret_cast<const bf16x8*>(Ah + kc * 32);
    bf16x8 al = *reinterpret_cast<const bf16x8*>(Al + kc * 32);
#pragma unroll
    for (int t = 0; t < 4; t++) {
      size_t base = (((size_t)kc * 4 + t) * 64 + l) * 8;
      bf16x8 bh = *reinterpret_cast<const bf16x8*>(W2h + base);
      bf16x8 bl = *reinterpret_cast<const bf16x8*>(W2l + base);
      acc[t] = __builtin_amdgcn_mfma_f32_16x16x32_bf16(ah, bh, acc[t], 0, 0, 0);
      acc[t] = __builtin_amdgcn_mfma_f32_16x16x32_bf16(ah, bl, acc[t], 0, 0, 0);
      acc[t] = __builtin_amdgcn_mfma_f32_16x16x32_bf16(al, bh, acc[t], 0, 0, 0);
    }
  }
  const int orow0 = blockIdx.x * 64 + w * 16 + (l >> 4) * 4;
  const int col16 = l & 15;
#pragma unroll
  for (int t = 0; t < 4; t++) {
    int col = t * 16 + col16;
#pragma unroll
    for (int r = 0; r < 4; r++) {
      int row = orow0 + r;
      if (row < M) h2b[(size_t)row * 64 + col] = f2b(acc[t][r]);
    }
  }
}

// ----------------------------------- project W1 @ a_src/a_dst -> va[128][8]
__global__ void k_vproj(const float* __restrict__ W1,
                        const float* __restrict__ a_src1,
                        const float* __restrict__ a_dst1,
                        float* __restrict__ va) {
  int g = blockIdx.x * 256 + threadIdx.x;
  if (g >= 1024) return;
  int k = g >> 3, j = g & 7;
  int h = j & 3;
  const float* a = (j < 4) ? a_src1 : a_dst1;
  float s = 0.f;
  for (int c = 0; c < 64; c++) s += W1[(size_t)k * 256 + h * 64 + c] * a[h * 64 + c];
  va[k * 8 + j] = s;
}

// --------------- scores from x: [N,8] = x[N,128]@va  + fused bf16 cast of x
__global__ __launch_bounds__(256) void k_scores_x(const float* __restrict__ x,
                                                  const float* __restrict__ va,
                                                  float* __restrict__ s_src,
                                                  float* __restrict__ s_dst,
                                                  unsigned short* __restrict__ xb,
                                                  int N) {
  int n = blockIdx.x * 4 + (threadIdx.x >> 6);
  if (n >= N) return;
  int lane = threadIdx.x & 63;
  float x0 = x[(size_t)n * 128 + lane];
  float x1 = x[(size_t)n * 128 + 64 + lane];
  xb[(size_t)n * 128 + lane] = f2b(x0);
  xb[(size_t)n * 128 + 64 + lane] = f2b(x1);
  float4 vs0 = *reinterpret_cast<const float4*>(va + lane * 8);
  float4 vd0 = *reinterpret_cast<const float4*>(va + lane * 8 + 4);
  float4 vs1 = *reinterpret_cast<const float4*>(va + (lane + 64) * 8);
  float4 vd1 = *reinterpret_cast<const float4*>(va + (lane + 64) * 8 + 4);
  float rs0 = x0 * vs0.x + x1 * vs1.x, rs1 = x0 * vs0.y + x1 * vs1.y;
  float rs2 = x0 * vs0.z + x1 * vs1.z, rs3 = x0 * vs0.w + x1 * vs1.w;
  float rd0 = x0 * vd0.x + x1 * vd1.x, rd1 = x0 * vd0.y + x1 * vd1.y;
  float rd2 = x0 * vd0.z + x1 * vd1.z, rd3 = x0 * vd0.w + x1 * vd1.w;
#pragma unroll
  for (int off = 32; off; off >>= 1) {
    rs0 += __shfl_xor(rs0, off, 64); rs1 += __shfl_xor(rs1, off, 64);
    rs2 += __shfl_xor(rs2, off, 64); rs3 += __shfl_xor(rs3, off, 64);
    rd0 += __shfl_xor(rd0, off, 64); rd1 += __shfl_xor(rd1, off, 64);
    rd2 += __shfl_xor(rd2, off, 64); rd3 += __shfl_xor(rd3, off, 64);
  }
  if (lane == 0) {
    float4 ss = {rs0, rs1, rs2, rs3};
    float4 dd = {rd0, rd1, rd2, rd3};
    *reinterpret_cast<float4*>(s_src + (size_t)n * 4) = ss;
    *reinterpret_cast<float4*>(s_dst + (size_t)n * 4) = dd;
  }
}

// ------------------------------------------- scores for layer 2 (bf16 input)
__global__ __launch_bounds__(256) void k_scores2(const unsigned short* __restrict__ h2b,
                                                 const float* __restrict__ a_src,
                                                 const float* __restrict__ a_dst,
                                                 float* __restrict__ s_src,
                                                 float* __restrict__ s_dst,
                                                 int N) {
  int n = blockIdx.x * 4 + (threadIdx.x >> 6);
  if (n >= N) return;
  int lane = threadIdx.x & 63;
  float hv = b2f(h2b[(size_t)n * 64 + lane]);
  float sv = hv * a_src[lane];
  float dv = hv * a_dst[lane];
#pragma unroll
  for (int off = 32; off; off >>= 1) {
    sv += __shfl_xor(sv, off, 64);
    dv += __shfl_xor(dv, off, 64);
  }
  if (lane == 0) {
    s_src[n] = sv;
    s_dst[n] = dv;
  }
}

// ----------------------------------------------- count init: 1 per node
__global__ void k_init1(int* __restrict__ count, int N) {
  int i = blockIdx.x * 256 + threadIdx.x;
  if (i < N) count[i] = 1;
}

// ------------------------- degree over real edges, 8 edges/thread (MLP)
__global__ void k_degree(const int* __restrict__ ei, int E,
                         int* __restrict__ count) {
  int base = (blockIdx.x * 256 + threadIdx.x) * 8;
  if (base >= E) return;
  const int* dsts = ei + E;
  if (base + 8 <= E && (E & 3) == 0) {
    int4 a = *reinterpret_cast<const int4*>(dsts + base);
    int4 b = *reinterpret_cast<const int4*>(dsts + base + 4);
    atomicAdd(&count[a.x], 1); atomicAdd(&count[a.y], 1);
    atomicAdd(&count[a.z], 1); atomicAdd(&count[a.w], 1);
    atomicAdd(&count[b.x], 1); atomicAdd(&count[b.y], 1);
    atomicAdd(&count[b.z], 1); atomicAdd(&count[b.w], 1);
  } else {
    for (int e = base; e < E && e < base + 8; e++) atomicAdd(&count[dsts[e]], 1);
  }
}

__global__ __launch_bounds__(1024) void k_scan(const int* __restrict__ count,
                                               int* __restrict__ row_ptr,
                                               int* __restrict__ cursor,
                                               int* __restrict__ src_sorted, int N) {
  __shared__ int warp_sums[16];
  __shared__ int carry_s;
  const int t = threadIdx.x;
  const int lane = t & 63, wid = t >> 6;
  if (t == 0) carry_s = 0;
  __syncthreads();
  for (int base = 0; base < N; base += 1024) {
    int i = base + t;
    int v = (i < N) ? count[i] : 0;
    int x = v;
#pragma unroll
    for (int off = 1; off < 64; off <<= 1) {
      int y = __shfl_up(x, off, 64);
      if (lane >= off) x += y;
    }
    if (lane == 63) warp_sums[wid] = x;
    __syncthreads();
    if (wid == 0) {
      int s = (lane < 16) ? warp_sums[lane] : 0;
#pragma unroll
      for (int off = 1; off < 16; off <<= 1) {
        int y = __shfl_up(s, off, 64);
        if (lane >= off) s += y;
      }
      if (lane < 16) warp_sums[lane] = s;
    }
    __syncthreads();
    int woff = (wid > 0) ? warp_sums[wid - 1] : 0;
    int incl = x + woff;
    int carry = carry_s;
    if (i < N) {
      int excl = carry + incl - v;
      row_ptr[i] = excl;
      cursor[i] = excl + 1;     // slot 0 reserved for self-loop
      src_sorted[excl] = i;     // self-loop placed here
    }
    __syncthreads();
    if (t == 1023) carry_s = carry + incl;
    __syncthreads();
  }
  if (t == 0) row_ptr[N] = carry_s;
}

// --------------- scatter: 8 edges/thread -> 8 atomics in flight (MLP)
__global__ void k_scatter(const int* __restrict__ ei, int E,
                          int* __restrict__ cursor,
                          int* __restrict__ src_sorted) {
  int base = (blockIdx.x * 256 + threadIdx.x) * 8;
  if (base >= E) return;
  if (base + 8 <= E && (E & 3) == 0) {
    int4 s0 = *reinterpret_cast<const int4*>(ei + base);
    int4 s1 = *reinterpret_cast<const int4*>(ei + base + 4);
    int4 d0 = *reinterpret_cast<const int4*>(ei + E + base);
    int4 d1 = *reinterpret_cast<const int4*>(ei + E + base + 4);
    int pos[8];
    pos[0] = atomicAdd(&cursor[d0.x], 1);
    pos[1] = atomicAdd(&cursor[d0.y], 1);
    pos[2] = atomicAdd(&cursor[d0.z], 1);
    pos[3] = atomicAdd(&cursor[d0.w], 1);
    pos[4] = atomicAdd(&cursor[d1.x], 1);
    pos[5] = atomicAdd(&cursor[d1.y], 1);
    pos[6] = atomicAdd(&cursor[d1.z], 1);
    pos[7] = atomicAdd(&cursor[d1.w], 1);
    src_sorted[pos[0]] = s0.x;
    src_sorted[pos[1]] = s0.y;
    src_sorted[pos[2]] = s0.z;
    src_sorted[pos[3]] = s0.w;
    src_sorted[pos[4]] = s1.x;
    src_sorted[pos[5]] = s1.y;
    src_sorted[pos[6]] = s1.z;
    src_sorted[pos[7]] = s1.w;
  } else {
    for (int e = base; e < E && e < base + 8; e++) {
      int pos = atomicAdd(&cursor[ei[E + e]], 1);
      src_sorted[pos] = ei[e];
    }
  }
}

// --------------- layer-1 edge weights in CSR order (coalesced writes)
__global__ __launch_bounds__(256) void k_w1csr(const int* __restrict__ row_ptr,
                                               const int* __restrict__ src_sorted,
                                               const float* __restrict__ s_src,
                                               const float* __restrict__ s_dst,
                                               float4* __restrict__ w1s, int N) {
  int n = blockIdx.x * 4 + (threadIdx.x >> 6);
  if (n >= N) return;
  int lane = threadIdx.x & 63;
  float4 sd = *reinterpret_cast<const float4*>(s_dst + (size_t)n * 4);
  int beg = row_ptr[n], end = row_ptr[n + 1];
  for (int p = beg + lane; p < end; p += 64) {
    int s = src_sorted[p];
    float4 ss = *reinterpret_cast<const float4*>(s_src + (size_t)s * 4);
    float4 w;
    w.x = leaky_exp(ss.x + sd.x);
    w.y = leaky_exp(ss.y + sd.y);
    w.z = leaky_exp(ss.z + sd.z);
    w.w = leaky_exp(ss.w + sd.w);
    w1s[p] = w;
  }
}

// --------------- layer-2 edge weights in CSR order
__global__ __launch_bounds__(256) void k_w2csr(const int* __restrict__ row_ptr,
                                               const int* __restrict__ src_sorted,
                                               const float* __restrict__ s2s,
                                               const float* __restrict__ s2d,
                                               float* __restrict__ w2s, int N) {
  int n = blockIdx.x * 4 + (threadIdx.x >> 6);
  if (n >= N) return;
  int lane = threadIdx.x & 63;
  float sdn = s2d[n];
  int beg = row_ptr[n], end = row_ptr[n + 1];
  for (int p = beg + lane; p < end; p += 64) {
    w2s[p] = leaky_exp(s2s[src_sorted[p]] + sdn);
  }
}

// ---------------------------- layer-1 aggregation over x (bf16), 4 heads
__global__ __launch_bounds__(256) void k_aggx(const unsigned short* __restrict__ xb,
                                              const int* __restrict__ row_ptr,
                                              const int* __restrict__ src_sorted,
                                              const float4* __restrict__ w1s,
                                              unsigned short* __restrict__ avgxb,
                                              int N) {
  int n = blockIdx.x * 4 + (threadIdx.x >> 6);
  if (n >= N) return;
  int lane = threadIdx.x & 63;
  int beg = row_ptr[n], end = row_ptr[n + 1];
  float acc[4][2] = {};
  float wsum[4] = {};
  int p = beg;
  for (; p + 4 <= end; p += 4) {
    int s[4];
    float4 w[4];
    unsigned int pk[4];
#pragma unroll
    for (int j = 0; j < 4; j++) s[j] = src_sorted[p + j];
#pragma unroll
    for (int j = 0; j < 4; j++) w[j] = w1s[p + j];
#pragma unroll
    for (int j = 0; j < 4; j++)
      pk[j] = *reinterpret_cast<const unsigned int*>(xb + (size_t)s[j] * 128 + lane * 2);
#pragma unroll
    for (int j = 0; j < 4; j++) {
      float x0 = __uint_as_float(pk[j] << 16);
      float x1 = __uint_as_float(pk[j] & 0xFFFF0000u);
      acc[0][0] = fmaf(w[j].x, x0, acc[0][0]); acc[0][1] = fmaf(w[j].x, x1, acc[0][1]);
      acc[1][0] = fmaf(w[j].y, x0, acc[1][0]); acc[1][1] = fmaf(w[j].y, x1, acc[1][1]);
      acc[2][0] = fmaf(w[j].z, x0, acc[2][0]); acc[2][1] = fmaf(w[j].z, x1, acc[2][1]);
      acc[3][0] = fmaf(w[j].w, x0, acc[3][0]); acc[3][1] = fmaf(w[j].w, x1, acc[3][1]);
      wsum[0] += w[j].x; wsum[1] += w[j].y; wsum[2] += w[j].z; wsum[3] += w[j].w;
    }
  }
  for (; p < end; p++) {
    int s = src_sorted[p];
    float4 w = w1s[p];
    unsigned int pk = *reinterpret_cast<const unsigned int*>(xb + (size_t)s * 128 + lane * 2);
    float x0 = __uint_as_float(pk << 16);
    float x1 = __uint_as_float(pk & 0xFFFF0000u);
    acc[0][0] = fmaf(w.x, x0, acc[0][0]); acc[0][1] = fmaf(w.x, x1, acc[0][1]);
    acc[1][0] = fmaf(w.y, x0, acc[1][0]); acc[1][1] = fmaf(w.y, x1, acc[1][1]);
    acc[2][0] = fmaf(w.z, x0, acc[2][0]); acc[2][1] = fmaf(w.z, x1, acc[2][1]);
    acc[3][0] = fmaf(w.w, x0, acc[3][0]); acc[3][1] = fmaf(w.w, x1, acc[3][1]);
    wsum[0] += w.x; wsum[1] += w.y; wsum[2] += w.z; wsum[3] += w.w;
  }
#pragma unroll
  for (int h = 0; h < 4; h++) {
    float inv = 1.f / (wsum[h] + 1e-16f);
    unsigned int pk = ((unsigned int)f2b(acc[h][1] * inv) << 16) | f2b(acc[h][0] * inv);
    *reinterpret_cast<unsigned int*>(avgxb + (size_t)n * 512 + h * 128 + lane * 2) = pk;
  }
}

// -------------------- layer-2 aggregation (bf16 h2) + fused relu + out head
__global__ __launch_bounds__(256) void k_agg2(const unsigned short* __restrict__ h2b,
                                              const int* __restrict__ row_ptr,
                                              const int* __restrict__ src_sorted,
                                              const float* __restrict__ w2s,
                                              const float* __restrict__ bias,
                                              const float* __restrict__ Wout,
                                              const float* __restrict__ bout,
                                              float* __restrict__ logits, int N) {
  int n = blockIdx.x * 4 + (threadIdx.x >> 6);
  if (n >= N) return;
  int lane = threadIdx.x & 63;
  int beg = row_ptr[n], end = row_ptr[n + 1];
  float acc = 0.f, wsum = 0.f;
  int p = beg;
  for (; p + 8 <= end; p += 8) {
    int s[8];
    float w[8];
    unsigned short hv[8];
#pragma unroll
    for (int j = 0; j < 8; j++) s[j] = src_sorted[p + j];
#pragma unroll
    for (int j = 0; j < 8; j++) w[j] = w2s[p + j];
#pragma unroll
    for (int j = 0; j < 8; j++) hv[j] = h2b[(size_t)s[j] * 64 + lane];
#pragma unroll
    for (int j = 0; j < 8; j++) {
      acc = fmaf(w[j], b2f(hv[j]), acc);
      wsum += w[j];
    }
  }
  for (; p < end; p++) {
    float w = w2s[p];
    acc = fmaf(w, b2f(h2b[(size_t)src_sorted[p] * 64 + lane]), acc);
    wsum += w;
  }
  float o = fmaxf(acc / (wsum + 1e-16f) + bias[lane], 0.f);
  float v = o * Wout[lane];
#pragma unroll
  for (int off = 32; off; off >>= 1) v += __shfl_xor(v, off, 64);
  if (lane == 0) logits[n] = v + bout[0];
}

extern "C" void kernel_launch(void* const* d_in, const int* in_sizes, int n_in,
                              void* d_out, int out_size, void* d_ws, size_t ws_size,
                              hipStream_t stream) {
  const float* x      = (const float*)d_in[0];
  const int*   ei     = (const int*)d_in[1];
  const float* W1     = (const float*)d_in[2];
  const float* a_src1 = (const float*)d_in[3];
  const float* a_dst1 = (const float*)d_in[4];
  const float* b1     = (const float*)d_in[5];
  const float* W2     = (const float*)d_in[6];
  const float* a_src2 = (const float*)d_in[7];
  const float* a_dst2 = (const float*)d_in[8];
  const float* b2     = (const float*)d_in[9];
  const float* Wout   = (const float*)d_in[10];
  const float* bout   = (const float*)d_in[11];
  float* logits = (float*)d_out;

  const int HC1  = in_sizes[5];           // 256
  const int F_IN = in_sizes[2] / HC1;     // 128
  const int N    = in_sizes[0] / F_IN;    // 50000
  const int E    = in_sizes[1] / 2;       // 1.6M
  const int Etot = E + N;

  char* w = (char*)d_ws;
  auto alloc = [&](size_t bytes) {
    char* p = w;
    w += (bytes + 255) & ~(size_t)255;
    return p;
  };
  // region A: xb (bf16 x); dead after k_aggx
  char* regA = alloc((size_t)N * 128 * sizeof(unsigned short));  // 12.8 MB
  unsigned short* xb = (unsigned short*)regA;
  // region B: avgxb (bf16); dead after k_gh_mfma -> h2b at offset 0,
  // w2s at offset 25.6 MB.
  char* regB = alloc((size_t)N * 512 * sizeof(unsigned short));  // 51.2 MB
  unsigned short* avgxb = (unsigned short*)regB;
  unsigned short* h2b = (unsigned short*)regB;
  float* w2s = (float*)(regB + (size_t)N * 256 * sizeof(unsigned short));
  // region C: w1s (26.4 MB), dead before k_gh_mfma writes hact hi/lo
  // (25.6 MB + 25.6 MB = 51.2 MB).
  char* regC = alloc((size_t)N * 256 * 4);                       // 51.2 MB
  unsigned short* hact_hi = (unsigned short*)regC;
  unsigned short* hact_lo = (unsigned short*)(regC + (size_t)N * 256 * sizeof(unsigned short));
  float4* w1s = (float4*)regC;
  float* s_src1  = (float*)alloc((size_t)N * 4 * 4);
  float* s_dst1  = (float*)alloc((size_t)N * 4 * 4);
  float* s2_src  = (float*)alloc((size_t)N * 4);
  float* s2_dst  = (float*)alloc((size_t)N * 4);
  float* va      = (float*)alloc(128 * 8 * 4);
  unsigned short* W1h = (unsigned short*)alloc(4096 * 8 * 2);    // 64 KB
  unsigned short* W1l = (unsigned short*)alloc(4096 * 8 * 2);
  unsigned short* W2h = (unsigned short*)alloc(2048 * 8 * 2);    // 32 KB
  unsigned short* W2l = (unsigned short*)alloc(2048 * 8 * 2);
  int* count     = (int*)alloc((size_t)N * 4);
  int* cursor    = (int*)alloc((size_t)N * 4);
  int* row_ptr   = (int*)alloc((size_t)(N + 1) * 4);
  int* src_sorted= (int*)alloc((size_t)Etot * 4);

  // ---- weight prep (tiny) ----
  k_prepW1<<<16, 256, 0, stream>>>(W1, W1h, W1l);
  k_prepW2<<<8, 256, 0, stream>>>(W2, W2h, W2l);
  k_vproj<<<4, 256, 0, stream>>>(W1, a_src1, a_dst1, va);

  // ---- layer 1 (h1 never materialized) ----
  k_scores_x<<<(N + 3) / 4, 256, 0, stream>>>(x, va, s_src1, s_dst1, xb, N);
  k_init1<<<(N + 255) / 256, 256, 0, stream>>>(count, N);
  k_degree<<<(E / 8 + 255) / 256, 256, 0, stream>>>(ei, E, count);
  k_scan<<<1, 1024, 0, stream>>>(count, row_ptr, cursor, src_sorted, N);
  k_scatter<<<(E / 8 + 255) / 256, 256, 0, stream>>>(ei, E, cursor, src_sorted);
  k_w1csr<<<(N + 3) / 4, 256, 0, stream>>>(row_ptr, src_sorted, s_src1, s_dst1, w1s, N);
  k_aggx<<<(N + 3) / 4, 256, 0, stream>>>(xb, row_ptr, src_sorted, w1s, avgxb, N);
  dim3 gh((N + 63) / 64, 1, 4);
  k_gh_mfma<<<gh, 256, 0, stream>>>(avgxb, W1h, W1l, b1, hact_hi, hact_lo, N);

  // ---- layer 2 ----
  k_g2_mfma<<<(N + 63) / 64, 256, 0, stream>>>(hact_hi, hact_lo, W2h, W2l, h2b, N);
  k_scores2<<<(N + 3) / 4, 256, 0, stream>>>(h2b, a_src2, a_dst2, s2_src, s2_dst, N);
  k_w2csr<<<(N + 3) / 4, 256, 0, stream>>>(row_ptr, src_sorted, s2_src, s2_dst, w2s, N);
  k_agg2<<<(N + 3) / 4, 256, 0, stream>>>(h2b, row_ptr, src_sorted, w2s,
                                          b2, Wout, bout, logits, N);
}

// Round 9
// 535.383 us; speedup vs baseline: 1.2161x; 1.1123x over previous
//
#include <hip/hip_runtime.h>
#include <hip/hip_bf16.h>

#define NEG_SLOPE 0.2f

using bf16x8 = __attribute__((ext_vector_type(8))) short;  // 8 bf16 (4 VGPRs)
using f32x4  = __attribute__((ext_vector_type(4))) float;  // 4 fp32 acc

// bf16 helpers: store with RNE, load via bit-shift (exact)
__device__ __forceinline__ unsigned short f2b(float f) {
  unsigned int u = __float_as_uint(f);
  unsigned int r = (u + 0x7FFFu + ((u >> 16) & 1u)) >> 16;
  return (unsigned short)r;
}
__device__ __forceinline__ float b2f(unsigned short v) {
  return __uint_as_float(((unsigned int)v) << 16);
}
__device__ __forceinline__ float leaky_exp(float e) {
  e = e > 0.f ? e : NEG_SLOPE * e;
  return __expf(e);
}

// ---------------- fused prep: count init + W1/W2 hi-lo swizzle + vproj -------
// blocks [0,16): prepW1; [16,24): prepW2; [24,28): vproj; [28,...): count=1.
__global__ void k_prep(const float* __restrict__ W1,
                       const float* __restrict__ W2,
                       const float* __restrict__ a_src1,
                       const float* __restrict__ a_dst1,
                       unsigned short* __restrict__ W1h,
                       unsigned short* __restrict__ W1l,
                       unsigned short* __restrict__ W2h,
                       unsigned short* __restrict__ W2l,
                       float* __restrict__ va,
                       int* __restrict__ count, int N) {
  int b = blockIdx.x;
  int t = threadIdx.x;
  if (b < 16) {                                  // --- prepW1 (4096 frags)
    int g = b * 256 + t;
    int l = g & 63, tt = (g >> 6) & 3, kc = (g >> 8) & 3, h = (g >> 10) & 3;
    int n = h * 64 + tt * 16 + (l & 15);
    int kbase = kc * 32 + (l >> 4) * 8;
    size_t base = ((((size_t)h * 4 + kc) * 4 + tt) * 64 + l) * 8;
#pragma unroll
    for (int j = 0; j < 8; j++) {
      float v = W1[(size_t)(kbase + j) * 256 + n];
      unsigned short hi = f2b(v);
      W1h[base + j] = hi;
      W1l[base + j] = f2b(v - b2f(hi));
    }
  } else if (b < 24) {                           // --- prepW2 (2048 frags)
    int g = (b - 16) * 256 + t;
    int l = g & 63, tt = (g >> 6) & 3, kc = (g >> 8) & 7;
    int n = tt * 16 + (l & 15);
    int kbase = kc * 32 + (l >> 4) * 8;
    size_t base = (((size_t)kc * 4 + tt) * 64 + l) * 8;
#pragma unroll
    for (int j = 0; j < 8; j++) {
      float v = W2[(size_t)(kbase + j) * 64 + n];
      unsigned short hi = f2b(v);
      W2h[base + j] = hi;
      W2l[base + j] = f2b(v - b2f(hi));
    }
  } else if (b < 28) {                           // --- vproj (1024 entries)
    int g = (b - 24) * 256 + t;
    int k = g >> 3, j = g & 7;
    int h = j & 3;
    const float* a = (j < 4) ? a_src1 : a_dst1;
    float s = 0.f;
    for (int c = 0; c < 64; c++) s += W1[(size_t)k * 256 + h * 64 + c] * a[h * 64 + c];
    va[k * 8 + j] = s;
  } else {                                       // --- count init = 1
    int i = (b - 28) * 256 + t;
    if (i < N) count[i] = 1;
  }
}

// ------------- layer-1 GEMM via MFMA: hact = relu(avgxb @ (W1h+W1l) + b1)
__global__ __launch_bounds__(256) void k_gh_mfma(const unsigned short* __restrict__ Ab,
                                                 const unsigned short* __restrict__ W1h,
                                                 const unsigned short* __restrict__ W1l,
                                                 const float* __restrict__ b1,
                                                 unsigned short* __restrict__ hact_hi,
                                                 unsigned short* __restrict__ hact_lo,
                                                 int M) {
  const int w = threadIdx.x >> 6, l = threadIdx.x & 63;
  const int h = blockIdx.z;
  const int rowA = blockIdx.x * 64 + w * 16 + (l & 15);
  const int rA = rowA < M ? rowA : M - 1;
  const int kg = l >> 4;
  const unsigned short* Aptr = Ab + (size_t)rA * 512 + h * 128 + kg * 8;
  f32x4 acc[4] = {{0.f, 0.f, 0.f, 0.f}, {0.f, 0.f, 0.f, 0.f},
                  {0.f, 0.f, 0.f, 0.f}, {0.f, 0.f, 0.f, 0.f}};
#pragma unroll
  for (int kc = 0; kc < 4; kc++) {
    bf16x8 a = *reinterpret_cast<const bf16x8*>(Aptr + kc * 32);
#pragma unroll
    for (int t = 0; t < 4; t++) {
      size_t base = ((((size_t)h * 4 + kc) * 4 + t) * 64 + l) * 8;
      bf16x8 bh = *reinterpret_cast<const bf16x8*>(W1h + base);
      bf16x8 bl = *reinterpret_cast<const bf16x8*>(W1l + base);
      acc[t] = __builtin_amdgcn_mfma_f32_16x16x32_bf16(a, bh, acc[t], 0, 0, 0);
      acc[t] = __builtin_amdgcn_mfma_f32_16x16x32_bf16(a, bl, acc[t], 0, 0, 0);
    }
  }
  const int orow0 = blockIdx.x * 64 + w * 16 + (l >> 4) * 4;
  const int col16 = l & 15;
#pragma unroll
  for (int t = 0; t < 4; t++) {
    int col = h * 64 + t * 16 + col16;
    float bb = b1[col];
#pragma unroll
    for (int r = 0; r < 4; r++) {
      int row = orow0 + r;
      if (row < M) {
        float v = fmaxf(acc[t][r] + bb, 0.f);
        unsigned short hi = f2b(v);
        hact_hi[(size_t)row * 256 + col] = hi;
        hact_lo[(size_t)row * 256 + col] = f2b(v - b2f(hi));
      }
    }
  }
}

// ------------- layer-2 GEMM via MFMA: h2b = (Ah+Al) @ (W2h+W2l), K=256
__global__ __launch_bounds__(256) void k_g2_mfma(const unsigned short* __restrict__ Ahi,
                                                 const unsigned short* __restrict__ Alo,
                                                 const unsigned short* __restrict__ W2h,
                                                 const unsigned short* __restrict__ W2l,
                                                 unsigned short* __restrict__ h2b,
                                                 int M) {
  const int w = threadIdx.x >> 6, l = threadIdx.x & 63;
  const int rowA = blockIdx.x * 64 + w * 16 + (l & 15);
  const int rA = rowA < M ? rowA : M - 1;
  const int kg = l >> 4;
  const unsigned short* Ah = Ahi + (size_t)rA * 256 + kg * 8;
  const unsigned short* Al = Alo + (size_t)rA * 256 + kg * 8;
  f32x4 acc[4] = {{0.f, 0.f, 0.f, 0.f}, {0.f, 0.f, 0.f, 0.f},
                  {0.f, 0.f, 0.f, 0.f}, {0.f, 0.f, 0.f, 0.f}};
#pragma unroll
  for (int kc = 0; kc < 8; kc++) {
    bf16x8 ah = *reinterpret_cast<const bf16x8*>(Ah + kc * 32);
    bf16x8 al = *reinterpret_cast<const bf16x8*>(Al + kc * 32);
#pragma unroll
    for (int t = 0; t < 4; t++) {
      size_t base = (((size_t)kc * 4 + t) * 64 + l) * 8;
      bf16x8 bh = *reinterpret_cast<const bf16x8*>(W2h + base);
      bf16x8 bl = *reinterpret_cast<const bf16x8*>(W2l + base);
      acc[t] = __builtin_amdgcn_mfma_f32_16x16x32_bf16(ah, bh, acc[t], 0, 0, 0);
      acc[t] = __builtin_amdgcn_mfma_f32_16x16x32_bf16(ah, bl, acc[t], 0, 0, 0);
      acc[t] = __builtin_amdgcn_mfma_f32_16x16x32_bf16(al, bh, acc[t], 0, 0, 0);
    }
  }
  const int orow0 = blockIdx.x * 64 + w * 16 + (l >> 4) * 4;
  const int col16 = l & 15;
#pragma unroll
  for (int t = 0; t < 4; t++) {
    int col = t * 16 + col16;
#pragma unroll
    for (int r = 0; r < 4; r++) {
      int row = orow0 + r;
      if (row < M) h2b[(size_t)row * 64 + col] = f2b(acc[t][r]);
    }
  }
}

// --------------- scores from x: [N,8] = x[N,128]@va  + fused bf16 cast of x
__global__ __launch_bounds__(256) void k_scores_x(const float* __restrict__ x,
                                                  const float* __restrict__ va,
                                                  float* __restrict__ s_src,
                                                  float* __restrict__ s_dst,
                                                  unsigned short* __restrict__ xb,
                                                  int N) {
  int n = blockIdx.x * 4 + (threadIdx.x >> 6);
  if (n >= N) return;
  int lane = threadIdx.x & 63;
  float x0 = x[(size_t)n * 128 + lane];
  float x1 = x[(size_t)n * 128 + 64 + lane];
  xb[(size_t)n * 128 + lane] = f2b(x0);
  xb[(size_t)n * 128 + 64 + lane] = f2b(x1);
  float4 vs0 = *reinterpret_cast<const float4*>(va + lane * 8);
  float4 vd0 = *reinterpret_cast<const float4*>(va + lane * 8 + 4);
  float4 vs1 = *reinterpret_cast<const float4*>(va + (lane + 64) * 8);
  float4 vd1 = *reinterpret_cast<const float4*>(va + (lane + 64) * 8 + 4);
  float rs0 = x0 * vs0.x + x1 * vs1.x, rs1 = x0 * vs0.y + x1 * vs1.y;
  float rs2 = x0 * vs0.z + x1 * vs1.z, rs3 = x0 * vs0.w + x1 * vs1.w;
  float rd0 = x0 * vd0.x + x1 * vd1.x, rd1 = x0 * vd0.y + x1 * vd1.y;
  float rd2 = x0 * vd0.z + x1 * vd1.z, rd3 = x0 * vd0.w + x1 * vd1.w;
#pragma unroll
  for (int off = 32; off; off >>= 1) {
    rs0 += __shfl_xor(rs0, off, 64); rs1 += __shfl_xor(rs1, off, 64);
    rs2 += __shfl_xor(rs2, off, 64); rs3 += __shfl_xor(rs3, off, 64);
    rd0 += __shfl_xor(rd0, off, 64); rd1 += __shfl_xor(rd1, off, 64);
    rd2 += __shfl_xor(rd2, off, 64); rd3 += __shfl_xor(rd3, off, 64);
  }
  if (lane == 0) {
    float4 ss = {rs0, rs1, rs2, rs3};
    float4 dd = {rd0, rd1, rd2, rd3};
    *reinterpret_cast<float4*>(s_src + (size_t)n * 4) = ss;
    *reinterpret_cast<float4*>(s_dst + (size_t)n * 4) = dd;
  }
}

// ------------------------------------------- scores for layer 2 (bf16 input)
__global__ __launch_bounds__(256) void k_scores2(const unsigned short* __restrict__ h2b,
                                                 const float* __restrict__ a_src,
                                                 const float* __restrict__ a_dst,
                                                 float* __restrict__ s_src,
                                                 float* __restrict__ s_dst,
                                                 int N) {
  int n = blockIdx.x * 4 + (threadIdx.x >> 6);
  if (n >= N) return;
  int lane = threadIdx.x & 63;
  float hv = b2f(h2b[(size_t)n * 64 + lane]);
  float sv = hv * a_src[lane];
  float dv = hv * a_dst[lane];
#pragma unroll
  for (int off = 32; off; off >>= 1) {
    sv += __shfl_xor(sv, off, 64);
    dv += __shfl_xor(dv, off, 64);
  }
  if (lane == 0) {
    s_src[n] = sv;
    s_dst[n] = dv;
  }
}

// ------------------------- degree over real edges, 8 edges/thread (MLP)
__global__ void k_degree(const int* __restrict__ ei, int E,
                         int* __restrict__ count) {
  int base = (blockIdx.x * 256 + threadIdx.x) * 8;
  if (base >= E) return;
  const int* dsts = ei + E;
  if (base + 8 <= E && (E & 3) == 0) {
    int4 a = *reinterpret_cast<const int4*>(dsts + base);
    int4 b = *reinterpret_cast<const int4*>(dsts + base + 4);
    atomicAdd(&count[a.x], 1); atomicAdd(&count[a.y], 1);
    atomicAdd(&count[a.z], 1); atomicAdd(&count[a.w], 1);
    atomicAdd(&count[b.x], 1); atomicAdd(&count[b.y], 1);
    atomicAdd(&count[b.z], 1); atomicAdd(&count[b.w], 1);
  } else {
    for (int e = base; e < E && e < base + 8; e++) atomicAdd(&count[dsts[e]], 1);
  }
}

// --------------- two-level scan: A = in-block exclusive + block totals
__global__ __launch_bounds__(1024) void k_scanA(const int* __restrict__ count,
                                                int* __restrict__ tmp_excl,
                                                int* __restrict__ blocksums, int N) {
  __shared__ int warp_sums[16];
  const int t = threadIdx.x;
  const int lane = t & 63, wid = t >> 6;
  int i = blockIdx.x * 1024 + t;
  int v = (i < N) ? count[i] : 0;
  int x = v;
#pragma unroll
  for (int off = 1; off < 64; off <<= 1) {
    int y = __shfl_up(x, off, 64);
    if (lane >= off) x += y;
  }
  if (lane == 63) warp_sums[wid] = x;
  __syncthreads();
  if (wid == 0) {
    int s = (lane < 16) ? warp_sums[lane] : 0;
#pragma unroll
    for (int off = 1; off < 16; off <<= 1) {
      int y = __shfl_up(s, off, 64);
      if (lane >= off) s += y;
    }
    if (lane < 16) warp_sums[lane] = s;
  }
  __syncthreads();
  int woff = (wid > 0) ? warp_sums[wid - 1] : 0;
  int incl = x + woff;
  if (i < N) tmp_excl[i] = incl - v;
  if (t == 1023) blocksums[blockIdx.x] = incl;
}

// --------------- B: scan block totals (nb <= 1024), write row_ptr[N]
__global__ __launch_bounds__(1024) void k_scanB(const int* __restrict__ blocksums,
                                                int* __restrict__ blockoff,
                                                int nb, int* __restrict__ row_ptr_last) {
  __shared__ int warp_sums[16];
  const int t = threadIdx.x;
  const int lane = t & 63, wid = t >> 6;
  int v = (t < nb) ? blocksums[t] : 0;
  int x = v;
#pragma unroll
  for (int off = 1; off < 64; off <<= 1) {
    int y = __shfl_up(x, off, 64);
    if (lane >= off) x += y;
  }
  if (lane == 63) warp_sums[wid] = x;
  __syncthreads();
  if (wid == 0) {
    int s = (lane < 16) ? warp_sums[lane] : 0;
#pragma unroll
    for (int off = 1; off < 16; off <<= 1) {
      int y = __shfl_up(s, off, 64);
      if (lane >= off) s += y;
    }
    if (lane < 16) warp_sums[lane] = s;
  }
  __syncthreads();
  int woff = (wid > 0) ? warp_sums[wid - 1] : 0;
  int incl = x + woff;
  if (t < nb) blockoff[t] = incl - v;
  if (t == nb - 1) *row_ptr_last = incl;
}

// --------------- C: finalize row_ptr / cursor / self-loop slot
__global__ __launch_bounds__(1024) void k_scanC(const int* __restrict__ tmp_excl,
                                                const int* __restrict__ blockoff,
                                                int* __restrict__ row_ptr,
                                                int* __restrict__ cursor,
                                                int* __restrict__ src_sorted, int N) {
  int i = blockIdx.x * 1024 + threadIdx.x;
  if (i >= N) return;
  int excl = tmp_excl[i] + blockoff[blockIdx.x];
  row_ptr[i] = excl;
  cursor[i] = excl + 1;     // slot 0 reserved for self-loop
  src_sorted[excl] = i;     // self-loop placed here
}

// --------------- scatter: 8 edges/thread -> 8 atomics in flight (MLP)
__global__ void k_scatter(const int* __restrict__ ei, int E,
                          int* __restrict__ cursor,
                          int* __restrict__ src_sorted) {
  int base = (blockIdx.x * 256 + threadIdx.x) * 8;
  if (base >= E) return;
  if (base + 8 <= E && (E & 3) == 0) {
    int4 s0 = *reinterpret_cast<const int4*>(ei + base);
    int4 s1 = *reinterpret_cast<const int4*>(ei + base + 4);
    int4 d0 = *reinterpret_cast<const int4*>(ei + E + base);
    int4 d1 = *reinterpret_cast<const int4*>(ei + E + base + 4);
    int pos[8];
    pos[0] = atomicAdd(&cursor[d0.x], 1);
    pos[1] = atomicAdd(&cursor[d0.y], 1);
    pos[2] = atomicAdd(&cursor[d0.z], 1);
    pos[3] = atomicAdd(&cursor[d0.w], 1);
    pos[4] = atomicAdd(&cursor[d1.x], 1);
    pos[5] = atomicAdd(&cursor[d1.y], 1);
    pos[6] = atomicAdd(&cursor[d1.z], 1);
    pos[7] = atomicAdd(&cursor[d1.w], 1);
    src_sorted[pos[0]] = s0.x;
    src_sorted[pos[1]] = s0.y;
    src_sorted[pos[2]] = s0.z;
    src_sorted[pos[3]] = s0.w;
    src_sorted[pos[4]] = s1.x;
    src_sorted[pos[5]] = s1.y;
    src_sorted[pos[6]] = s1.z;
    src_sorted[pos[7]] = s1.w;
  } else {
    for (int e = base; e < E && e < base + 8; e++) {
      int pos = atomicAdd(&cursor[ei[E + e]], 1);
      src_sorted[pos] = ei[e];
    }
  }
}

// --------------- layer-1 edge weights in CSR order (coalesced writes)
__global__ __launch_bounds__(256) void k_w1csr(const int* __restrict__ row_ptr,
                                               const int* __restrict__ src_sorted,
                                               const float* __restrict__ s_src,
                                               const float* __restrict__ s_dst,
                                               float4* __restrict__ w1s, int N) {
  int n = blockIdx.x * 4 + (threadIdx.x >> 6);
  if (n >= N) return;
  int lane = threadIdx.x & 63;
  float4 sd = *reinterpret_cast<const float4*>(s_dst + (size_t)n * 4);
  int beg = row_ptr[n], end = row_ptr[n + 1];
  for (int p = beg + lane; p < end; p += 64) {
    int s = src_sorted[p];
    float4 ss = *reinterpret_cast<const float4*>(s_src + (size_t)s * 4);
    float4 w;
    w.x = leaky_exp(ss.x + sd.x);
    w.y = leaky_exp(ss.y + sd.y);
    w.z = leaky_exp(ss.z + sd.z);
    w.w = leaky_exp(ss.w + sd.w);
    w1s[p] = w;
  }
}

// --------------- layer-2 edge weights in CSR order
__global__ __launch_bounds__(256) void k_w2csr(const int* __restrict__ row_ptr,
                                               const int* __restrict__ src_sorted,
                                               const float* __restrict__ s2s,
                                               const float* __restrict__ s2d,
                                               float* __restrict__ w2s, int N) {
  int n = blockIdx.x * 4 + (threadIdx.x >> 6);
  if (n >= N) return;
  int lane = threadIdx.x & 63;
  float sdn = s2d[n];
  int beg = row_ptr[n], end = row_ptr[n + 1];
  for (int p = beg + lane; p < end; p += 64) {
    w2s[p] = leaky_exp(s2s[src_sorted[p]] + sdn);
  }
}

// ---------------------------- layer-1 aggregation over x (bf16), 4 heads
__global__ __launch_bounds__(256) void k_aggx(const unsigned short* __restrict__ xb,
                                              const int* __restrict__ row_ptr,
                                              const int* __restrict__ src_sorted,
                                              const float4* __restrict__ w1s,
                                              unsigned short* __restrict__ avgxb,
                                              int N) {
  int n = blockIdx.x * 4 + (threadIdx.x >> 6);
  if (n >= N) return;
  int lane = threadIdx.x & 63;
  int beg = row_ptr[n], end = row_ptr[n + 1];
  float acc[4][2] = {};
  float wsum[4] = {};
  int p = beg;
  for (; p + 4 <= end; p += 4) {
    int s[4];
    float4 w[4];
    unsigned int pk[4];
#pragma unroll
    for (int j = 0; j < 4; j++) s[j] = src_sorted[p + j];
#pragma unroll
    for (int j = 0; j < 4; j++) w[j] = w1s[p + j];
#pragma unroll
    for (int j = 0; j < 4; j++)
      pk[j] = *reinterpret_cast<const unsigned int*>(xb + (size_t)s[j] * 128 + lane * 2);
#pragma unroll
    for (int j = 0; j < 4; j++) {
      float x0 = __uint_as_float(pk[j] << 16);
      float x1 = __uint_as_float(pk[j] & 0xFFFF0000u);
      acc[0][0] = fmaf(w[j].x, x0, acc[0][0]); acc[0][1] = fmaf(w[j].x, x1, acc[0][1]);
      acc[1][0] = fmaf(w[j].y, x0, acc[1][0]); acc[1][1] = fmaf(w[j].y, x1, acc[1][1]);
      acc[2][0] = fmaf(w[j].z, x0, acc[2][0]); acc[2][1] = fmaf(w[j].z, x1, acc[2][1]);
      acc[3][0] = fmaf(w[j].w, x0, acc[3][0]); acc[3][1] = fmaf(w[j].w, x1, acc[3][1]);
      wsum[0] += w[j].x; wsum[1] += w[j].y; wsum[2] += w[j].z; wsum[3] += w[j].w;
    }
  }
  for (; p < end; p++) {
    int s = src_sorted[p];
    float4 w = w1s[p];
    unsigned int pk = *reinterpret_cast<const unsigned int*>(xb + (size_t)s * 128 + lane * 2);
    float x0 = __uint_as_float(pk << 16);
    float x1 = __uint_as_float(pk & 0xFFFF0000u);
    acc[0][0] = fmaf(w.x, x0, acc[0][0]); acc[0][1] = fmaf(w.x, x1, acc[0][1]);
    acc[1][0] = fmaf(w.y, x0, acc[1][0]); acc[1][1] = fmaf(w.y, x1, acc[1][1]);
    acc[2][0] = fmaf(w.z, x0, acc[2][0]); acc[2][1] = fmaf(w.z, x1, acc[2][1]);
    acc[3][0] = fmaf(w.w, x0, acc[3][0]); acc[3][1] = fmaf(w.w, x1, acc[3][1]);
    wsum[0] += w.x; wsum[1] += w.y; wsum[2] += w.z; wsum[3] += w.w;
  }
#pragma unroll
  for (int h = 0; h < 4; h++) {
    float inv = 1.f / (wsum[h] + 1e-16f);
    unsigned int pk = ((unsigned int)f2b(acc[h][1] * inv) << 16) | f2b(acc[h][0] * inv);
    *reinterpret_cast<unsigned int*>(avgxb + (size_t)n * 512 + h * 128 + lane * 2) = pk;
  }
}

// -------------------- layer-2 aggregation (bf16 h2) + fused relu + out head
__global__ __launch_bounds__(256) void k_agg2(const unsigned short* __restrict__ h2b,
                                              const int* __restrict__ row_ptr,
                                              const int* __restrict__ src_sorted,
                                              const float* __restrict__ w2s,
                                              const float* __restrict__ bias,
                                              const float* __restrict__ Wout,
                                              const float* __restrict__ bout,
                                              float* __restrict__ logits, int N) {
  int n = blockIdx.x * 4 + (threadIdx.x >> 6);
  if (n >= N) return;
  int lane = threadIdx.x & 63;
  int beg = row_ptr[n], end = row_ptr[n + 1];
  float acc = 0.f, wsum = 0.f;
  int p = beg;
  for (; p + 8 <= end; p += 8) {
    int s[8];
    float w[8];
    unsigned short hv[8];
#pragma unroll
    for (int j = 0; j < 8; j++) s[j] = src_sorted[p + j];
#pragma unroll
    for (int j = 0; j < 8; j++) w[j] = w2s[p + j];
#pragma unroll
    for (int j = 0; j < 8; j++) hv[j] = h2b[(size_t)s[j] * 64 + lane];
#pragma unroll
    for (int j = 0; j < 8; j++) {
      acc = fmaf(w[j], b2f(hv[j]), acc);
      wsum += w[j];
    }
  }
  for (; p < end; p++) {
    float w = w2s[p];
    acc = fmaf(w, b2f(h2b[(size_t)src_sorted[p] * 64 + lane]), acc);
    wsum += w;
  }
  float o = fmaxf(acc / (wsum + 1e-16f) + bias[lane], 0.f);
  float v = o * Wout[lane];
#pragma unroll
  for (int off = 32; off; off >>= 1) v += __shfl_xor(v, off, 64);
  if (lane == 0) logits[n] = v + bout[0];
}

extern "C" void kernel_launch(void* const* d_in, const int* in_sizes, int n_in,
                              void* d_out, int out_size, void* d_ws, size_t ws_size,
                              hipStream_t stream) {
  const float* x      = (const float*)d_in[0];
  const int*   ei     = (const int*)d_in[1];
  const float* W1     = (const float*)d_in[2];
  const float* a_src1 = (const float*)d_in[3];
  const float* a_dst1 = (const float*)d_in[4];
  const float* b1     = (const float*)d_in[5];
  const float* W2     = (const float*)d_in[6];
  const float* a_src2 = (const float*)d_in[7];
  const float* a_dst2 = (const float*)d_in[8];
  const float* b2     = (const float*)d_in[9];
  const float* Wout   = (const float*)d_in[10];
  const float* bout   = (const float*)d_in[11];
  float* logits = (float*)d_out;

  const int HC1  = in_sizes[5];           // 256
  const int F_IN = in_sizes[2] / HC1;     // 128
  const int N    = in_sizes[0] / F_IN;    // 50000
  const int E    = in_sizes[1] / 2;       // 1.6M
  const int Etot = E + N;

  char* w = (char*)d_ws;
  auto alloc = [&](size_t bytes) {
    char* p = w;
    w += (bytes + 255) & ~(size_t)255;
    return p;
  };
  // region A: xb (bf16 x); dead after k_aggx
  char* regA = alloc((size_t)N * 128 * sizeof(unsigned short));  // 12.8 MB
  unsigned short* xb = (unsigned short*)regA;
  // region B: avgxb (bf16); dead after k_gh_mfma -> h2b at offset 0,
  // w2s at offset 25.6 MB.
  char* regB = alloc((size_t)N * 512 * sizeof(unsigned short));  // 51.2 MB
  unsigned short* avgxb = (unsigned short*)regB;
  unsigned short* h2b = (unsigned short*)regB;
  float* w2s = (float*)(regB + (size_t)N * 256 * sizeof(unsigned short));
  // region C: w1s (26.4 MB), dead before k_gh_mfma writes hact hi/lo
  char* regC = alloc((size_t)N * 256 * 4);                       // 51.2 MB
  unsigned short* hact_hi = (unsigned short*)regC;
  unsigned short* hact_lo = (unsigned short*)(regC + (size_t)N * 256 * sizeof(unsigned short));
  float4* w1s = (float4*)regC;
  float* s_src1  = (float*)alloc((size_t)N * 4 * 4);
  float* s_dst1  = (float*)alloc((size_t)N * 4 * 4);
  float* s2_src  = (float*)alloc((size_t)N * 4);
  float* s2_dst  = (float*)alloc((size_t)N * 4);
  float* va      = (float*)alloc(128 * 8 * 4);
  unsigned short* W1h = (unsigned short*)alloc(4096 * 8 * 2);    // 64 KB
  unsigned short* W1l = (unsigned short*)alloc(4096 * 8 * 2);
  unsigned short* W2h = (unsigned short*)alloc(2048 * 8 * 2);    // 32 KB
  unsigned short* W2l = (unsigned short*)alloc(2048 * 8 * 2);
  int* count     = (int*)alloc((size_t)N * 4);
  int* cursor    = (int*)alloc((size_t)N * 4);
  int* row_ptr   = (int*)alloc((size_t)(N + 1) * 4);
  int* src_sorted= (int*)alloc((size_t)Etot * 4);
  int* blocksums = (int*)alloc(1024 * 4);
  int* blockoff  = (int*)alloc(1024 * 4);

  const int nb = (N + 1023) / 1024;   // 49 for N=50000 (<=1024 supported)

  // ---- fused prep: count=1, W hi/lo swizzles, vproj ----
  k_prep<<<28 + (N + 255) / 256, 256, 0, stream>>>(W1, W2, a_src1, a_dst1,
                                                   W1h, W1l, W2h, W2l, va, count, N);

  // ---- layer 1 (h1 never materialized) ----
  k_scores_x<<<(N + 3) / 4, 256, 0, stream>>>(x, va, s_src1, s_dst1, xb, N);
  k_degree<<<(E / 8 + 255) / 256, 256, 0, stream>>>(ei, E, count);
  k_scanA<<<nb, 1024, 0, stream>>>(count, row_ptr, blocksums, N);
  k_scanB<<<1, 1024, 0, stream>>>(blocksums, blockoff, nb, row_ptr + N);
  k_scanC<<<nb, 1024, 0, stream>>>(row_ptr, blockoff, row_ptr, cursor, src_sorted, N);
  k_scatter<<<(E / 8 + 255) / 256, 256, 0, stream>>>(ei, E, cursor, src_sorted);
  k_w1csr<<<(N + 3) / 4, 256, 0, stream>>>(row_ptr, src_sorted, s_src1, s_dst1, w1s, N);
  k_aggx<<<(N + 3) / 4, 256, 0, stream>>>(xb, row_ptr, src_sorted, w1s, avgxb, N);
  dim3 gh((N + 63) / 64, 1, 4);
  k_gh_mfma<<<gh, 256, 0, stream>>>(avgxb, W1h, W1l, b1, hact_hi, hact_lo, N);

  // ---- layer 2 ----
  k_g2_mfma<<<(N + 63) / 64, 256, 0, stream>>>(hact_hi, hact_lo, W2h, W2l, h2b, N);
  k_scores2<<<(N + 3) / 4, 256, 0, stream>>>(h2b, a_src2, a_dst2, s2_src, s2_dst, N);
  k_w2csr<<<(N + 3) / 4, 256, 0, stream>>>(row_ptr, src_sorted, s2_src, s2_dst, w2s, N);
  k_agg2<<<(N + 3) / 4, 256, 0, stream>>>(h2b, row_ptr, src_sorted, w2s,
                                          b2, Wout, bout, logits, N);
}

// Round 10
// 425.280 us; speedup vs baseline: 1.5310x; 1.2589x over previous
//
#include <hip/hip_runtime.h>
#include <hip/hip_bf16.h>

#define NEG_SLOPE 0.2f

using bf16x8 = __attribute__((ext_vector_type(8))) short;  // 8 bf16 (4 VGPRs)
using f32x4  = __attribute__((ext_vector_type(4))) float;  // 4 fp32 acc

// bf16 helpers: store with RNE, load via bit-shift (exact)
__device__ __forceinline__ unsigned short f2b(float f) {
  unsigned int u = __float_as_uint(f);
  unsigned int r = (u + 0x7FFFu + ((u >> 16) & 1u)) >> 16;
  return (unsigned short)r;
}
__device__ __forceinline__ float b2f(unsigned short v) {
  return __uint_as_float(((unsigned int)v) << 16);
}
__device__ __forceinline__ float leaky_exp(float e) {
  e = e > 0.f ? e : NEG_SLOPE * e;
  return __expf(e);
}

// ---------------- fused prep: W1/W2 hi-lo swizzle + vproj (28 blocks) -------
__global__ void k_prep(const float* __restrict__ W1,
                       const float* __restrict__ W2,
                       const float* __restrict__ a_src1,
                       const float* __restrict__ a_dst1,
                       unsigned short* __restrict__ W1h,
                       unsigned short* __restrict__ W1l,
                       unsigned short* __restrict__ W2h,
                       unsigned short* __restrict__ W2l,
                       float* __restrict__ va) {
  int b = blockIdx.x;
  int t = threadIdx.x;
  if (b < 16) {                                  // --- prepW1 (4096 frags)
    int g = b * 256 + t;
    int l = g & 63, tt = (g >> 6) & 3, kc = (g >> 8) & 3, h = (g >> 10) & 3;
    int n = h * 64 + tt * 16 + (l & 15);
    int kbase = kc * 32 + (l >> 4) * 8;
    size_t base = ((((size_t)h * 4 + kc) * 4 + tt) * 64 + l) * 8;
#pragma unroll
    for (int j = 0; j < 8; j++) {
      float v = W1[(size_t)(kbase + j) * 256 + n];
      unsigned short hi = f2b(v);
      W1h[base + j] = hi;
      W1l[base + j] = f2b(v - b2f(hi));
    }
  } else if (b < 24) {                           // --- prepW2 (2048 frags)
    int g = (b - 16) * 256 + t;
    int l = g & 63, tt = (g >> 6) & 3, kc = (g >> 8) & 7;
    int n = tt * 16 + (l & 15);
    int kbase = kc * 32 + (l >> 4) * 8;
    size_t base = (((size_t)kc * 4 + tt) * 64 + l) * 8;
#pragma unroll
    for (int j = 0; j < 8; j++) {
      float v = W2[(size_t)(kbase + j) * 64 + n];
      unsigned short hi = f2b(v);
      W2h[base + j] = hi;
      W2l[base + j] = f2b(v - b2f(hi));
    }
  } else {                                       // --- vproj (1024 entries)
    int g = (b - 24) * 256 + t;
    int k = g >> 3, j = g & 7;
    int h = j & 3;
    const float* a = (j < 4) ? a_src1 : a_dst1;
    float s = 0.f;
    for (int c = 0; c < 64; c++) s += W1[(size_t)k * 256 + h * 64 + c] * a[h * 64 + c];
    va[k * 8 + j] = s;
  }
}

// ------------- layer-1 GEMM via MFMA: hact = relu(avgxb @ (W1h+W1l) + b1)
__global__ __launch_bounds__(256) void k_gh_mfma(const unsigned short* __restrict__ Ab,
                                                 const unsigned short* __restrict__ W1h,
                                                 const unsigned short* __restrict__ W1l,
                                                 const float* __restrict__ b1,
                                                 unsigned short* __restrict__ hact_hi,
                                                 unsigned short* __restrict__ hact_lo,
                                                 int M) {
  const int w = threadIdx.x >> 6, l = threadIdx.x & 63;
  const int h = blockIdx.z;
  const int rowA = blockIdx.x * 64 + w * 16 + (l & 15);
  const int rA = rowA < M ? rowA : M - 1;
  const int kg = l >> 4;
  const unsigned short* Aptr = Ab + (size_t)rA * 512 + h * 128 + kg * 8;
  f32x4 acc[4] = {{0.f, 0.f, 0.f, 0.f}, {0.f, 0.f, 0.f, 0.f},
                  {0.f, 0.f, 0.f, 0.f}, {0.f, 0.f, 0.f, 0.f}};
#pragma unroll
  for (int kc = 0; kc < 4; kc++) {
    bf16x8 a = *reinterpret_cast<const bf16x8*>(Aptr + kc * 32);
#pragma unroll
    for (int t = 0; t < 4; t++) {
      size_t base = ((((size_t)h * 4 + kc) * 4 + t) * 64 + l) * 8;
      bf16x8 bh = *reinterpret_cast<const bf16x8*>(W1h + base);
      bf16x8 bl = *reinterpret_cast<const bf16x8*>(W1l + base);
      acc[t] = __builtin_amdgcn_mfma_f32_16x16x32_bf16(a, bh, acc[t], 0, 0, 0);
      acc[t] = __builtin_amdgcn_mfma_f32_16x16x32_bf16(a, bl, acc[t], 0, 0, 0);
    }
  }
  const int orow0 = blockIdx.x * 64 + w * 16 + (l >> 4) * 4;
  const int col16 = l & 15;
#pragma unroll
  for (int t = 0; t < 4; t++) {
    int col = h * 64 + t * 16 + col16;
    float bb = b1[col];
#pragma unroll
    for (int r = 0; r < 4; r++) {
      int row = orow0 + r;
      if (row < M) {
        float v = fmaxf(acc[t][r] + bb, 0.f);
        unsigned short hi = f2b(v);
        hact_hi[(size_t)row * 256 + col] = hi;
        hact_lo[(size_t)row * 256 + col] = f2b(v - b2f(hi));
      }
    }
  }
}

// ------------- layer-2 GEMM via MFMA: h2b = (Ah+Al) @ (W2h+W2l), K=256
__global__ __launch_bounds__(256) void k_g2_mfma(const unsigned short* __restrict__ Ahi,
                                                 const unsigned short* __restrict__ Alo,
                                                 const unsigned short* __restrict__ W2h,
                                                 const unsigned short* __restrict__ W2l,
                                                 unsigned short* __restrict__ h2b,
                                                 int M) {
  const int w = threadIdx.x >> 6, l = threadIdx.x & 63;
  const int rowA = blockIdx.x * 64 + w * 16 + (l & 15);
  const int rA = rowA < M ? rowA : M - 1;
  const int kg = l >> 4;
  const unsigned short* Ah = Ahi + (size_t)rA * 256 + kg * 8;
  const unsigned short* Al = Alo + (size_t)rA * 256 + kg * 8;
  f32x4 acc[4] = {{0.f, 0.f, 0.f, 0.f}, {0.f, 0.f, 0.f, 0.f},
                  {0.f, 0.f, 0.f, 0.f}, {0.f, 0.f, 0.f, 0.f}};
#pragma unroll
  for (int kc = 0; kc < 8; kc++) {
    bf16x8 ah = *reinterpret_cast<const bf16x8*>(Ah + kc * 32);
    bf16x8 al = *reinterpret_cast<const bf16x8*>(Al + kc * 32);
#pragma unroll
    for (int t = 0; t < 4; t++) {
      size_t base = (((size_t)kc * 4 + t) * 64 + l) * 8;
      bf16x8 bh = *reinterpret_cast<const bf16x8*>(W2h + base);
      bf16x8 bl = *reinterpret_cast<const bf16x8*>(W2l + base);
      acc[t] = __builtin_amdgcn_mfma_f32_16x16x32_bf16(ah, bh, acc[t], 0, 0, 0);
      acc[t] = __builtin_amdgcn_mfma_f32_16x16x32_bf16(ah, bl, acc[t], 0, 0, 0);
      acc[t] = __builtin_amdgcn_mfma_f32_16x16x32_bf16(al, bh, acc[t], 0, 0, 0);
    }
  }
  const int orow0 = blockIdx.x * 64 + w * 16 + (l >> 4) * 4;
  const int col16 = l & 15;
#pragma unroll
  for (int t = 0; t < 4; t++) {
    int col = t * 16 + col16;
#pragma unroll
    for (int r = 0; r < 4; r++) {
      int row = orow0 + r;
      if (row < M) h2b[(size_t)row * 64 + col] = f2b(acc[t][r]);
    }
  }
}

// --------------- scores from x: [N,8] = x[N,128]@va  + fused bf16 cast of x
__global__ __launch_bounds__(256) void k_scores_x(const float* __restrict__ x,
                                                  const float* __restrict__ va,
                                                  float* __restrict__ s_src,
                                                  float* __restrict__ s_dst,
                                                  unsigned short* __restrict__ xb,
                                                  int N) {
  int n = blockIdx.x * 4 + (threadIdx.x >> 6);
  if (n >= N) return;
  int lane = threadIdx.x & 63;
  float x0 = x[(size_t)n * 128 + lane];
  float x1 = x[(size_t)n * 128 + 64 + lane];
  xb[(size_t)n * 128 + lane] = f2b(x0);
  xb[(size_t)n * 128 + 64 + lane] = f2b(x1);
  float4 vs0 = *reinterpret_cast<const float4*>(va + lane * 8);
  float4 vd0 = *reinterpret_cast<const float4*>(va + lane * 8 + 4);
  float4 vs1 = *reinterpret_cast<const float4*>(va + (lane + 64) * 8);
  float4 vd1 = *reinterpret_cast<const float4*>(va + (lane + 64) * 8 + 4);
  float rs0 = x0 * vs0.x + x1 * vs1.x, rs1 = x0 * vs0.y + x1 * vs1.y;
  float rs2 = x0 * vs0.z + x1 * vs1.z, rs3 = x0 * vs0.w + x1 * vs1.w;
  float rd0 = x0 * vd0.x + x1 * vd1.x, rd1 = x0 * vd0.y + x1 * vd1.y;
  float rd2 = x0 * vd0.z + x1 * vd1.z, rd3 = x0 * vd0.w + x1 * vd1.w;
#pragma unroll
  for (int off = 32; off; off >>= 1) {
    rs0 += __shfl_xor(rs0, off, 64); rs1 += __shfl_xor(rs1, off, 64);
    rs2 += __shfl_xor(rs2, off, 64); rs3 += __shfl_xor(rs3, off, 64);
    rd0 += __shfl_xor(rd0, off, 64); rd1 += __shfl_xor(rd1, off, 64);
    rd2 += __shfl_xor(rd2, off, 64); rd3 += __shfl_xor(rd3, off, 64);
  }
  if (lane == 0) {
    float4 ss = {rs0, rs1, rs2, rs3};
    float4 dd = {rd0, rd1, rd2, rd3};
    *reinterpret_cast<float4*>(s_src + (size_t)n * 4) = ss;
    *reinterpret_cast<float4*>(s_dst + (size_t)n * 4) = dd;
  }
}

// ------------------------------------------- scores for layer 2 (bf16 input)
__global__ __launch_bounds__(256) void k_scores2(const unsigned short* __restrict__ h2b,
                                                 const float* __restrict__ a_src,
                                                 const float* __restrict__ a_dst,
                                                 float* __restrict__ s_src,
                                                 float* __restrict__ s_dst,
                                                 int N) {
  int n = blockIdx.x * 4 + (threadIdx.x >> 6);
  if (n >= N) return;
  int lane = threadIdx.x & 63;
  float hv = b2f(h2b[(size_t)n * 64 + lane]);
  float sv = hv * a_src[lane];
  float dv = hv * a_dst[lane];
#pragma unroll
  for (int off = 32; off; off >>= 1) {
    sv += __shfl_xor(sv, off, 64);
    dv += __shfl_xor(dv, off, 64);
  }
  if (lane == 0) {
    s_src[n] = sv;
    s_dst[n] = dv;
  }
}

// =================== MSD bucket sort CSR build (no per-element returning
// =================== global atomics) ========================================
// Pass A: coarse bucket = dst>>8 (196 buckets).
__global__ void k_histA(const int* __restrict__ ei, int E, int Etot,
                        int* __restrict__ ghist) {
  __shared__ int lh[256];
  int t = threadIdx.x;
  lh[t] = 0;
  __syncthreads();
  int base = (blockIdx.x * 256 + t) * 8;
#pragma unroll
  for (int j = 0; j < 8; j++) {
    int e = base + j;
    if (e < Etot) {
      int dst = (e < E) ? ei[E + e] : (e - E);
      atomicAdd(&lh[dst >> 8], 1);
    }
  }
  __syncthreads();
  if (lh[t]) atomicAdd(&ghist[t], lh[t]);
}

// scan 196 bucket counts -> bucketStart[0..196], gcursor
__global__ __launch_bounds__(256) void k_scan196(const int* __restrict__ ghist,
                                                 int* __restrict__ bstart,
                                                 int* __restrict__ gcur,
                                                 int nbuck, int Etot) {
  __shared__ int ws[4];
  int t = threadIdx.x;
  int lane = t & 63, wid = t >> 6;
  int v = (t < nbuck) ? ghist[t] : 0;
  int x = v;
#pragma unroll
  for (int off = 1; off < 64; off <<= 1) {
    int y = __shfl_up(x, off, 64);
    if (lane >= off) x += y;
  }
  if (lane == 63) ws[wid] = x;
  __syncthreads();
  if (t == 0) {
    int a0 = ws[0], a1 = ws[1], a2 = ws[2];
    ws[0] = 0; ws[1] = a0; ws[2] = a0 + a1; ws[3] = a0 + a1 + a2;
  }
  __syncthreads();
  int excl = x - v + ws[wid];
  if (t < nbuck) {
    bstart[t] = excl;
    gcur[t] = excl;
  }
  if (t == 0) bstart[nbuck] = Etot;
}

// scatter into coarse buckets: one returning atomic per (block,bucket).
__global__ void k_scatterA(const int* __restrict__ ei, int E, int Etot,
                           int* __restrict__ gcur,
                           int* __restrict__ keys1,
                           int* __restrict__ vals1) {
  __shared__ int lh[256];
  int t = threadIdx.x;
  lh[t] = 0;
  __syncthreads();
  int base = (blockIdx.x * 256 + t) * 8;
  int dsts[8], srcs[8];
#pragma unroll
  for (int j = 0; j < 8; j++) {
    int e = base + j;
    if (e < Etot) {
      int d, s;
      if (e < E) { d = ei[E + e]; s = ei[e]; }
      else       { d = s = e - E; }
      dsts[j] = d; srcs[j] = s;
      atomicAdd(&lh[d >> 8], 1);
    } else dsts[j] = -1;
  }
  __syncthreads();
  {
    int c = lh[t];
    lh[t] = c ? atomicAdd(&gcur[t], c) : 0;   // reserve contiguous range
  }
  __syncthreads();
#pragma unroll
  for (int j = 0; j < 8; j++) {
    if (dsts[j] >= 0) {
      int pos = atomicAdd(&lh[dsts[j] >> 8], 1);  // LDS cursor -> global pos
      keys1[pos] = dsts[j];
      vals1[pos] = srcs[j];
    }
  }
}

// Pass B: per-bucket LDS counting sort on dst&255; emits src_sorted + row_ptr.
__global__ __launch_bounds__(256) void k_sortB(const int* __restrict__ keys1,
                                               const int* __restrict__ vals1,
                                               const int* __restrict__ bstart,
                                               int* __restrict__ src_sorted,
                                               int* __restrict__ row_ptr,
                                               int N, int Etot) {
  __shared__ int lh[256];
  __shared__ int ws[4];
  int b = blockIdx.x;
  int t = threadIdx.x;
  int lane = t & 63, wid = t >> 6;
  int s = bstart[b], e2 = bstart[b + 1];
  lh[t] = 0;
  __syncthreads();
  for (int p = s + t; p < e2; p += 256)
    atomicAdd(&lh[keys1[p] & 255], 1);
  __syncthreads();
  int v = lh[t];
  int x = v;
#pragma unroll
  for (int off = 1; off < 64; off <<= 1) {
    int y = __shfl_up(x, off, 64);
    if (lane >= off) x += y;
  }
  if (lane == 63) ws[wid] = x;
  __syncthreads();
  if (t == 0) {
    int a0 = ws[0], a1 = ws[1], a2 = ws[2];
    ws[0] = 0; ws[1] = a0; ws[2] = a0 + a1; ws[3] = a0 + a1 + a2;
  }
  __syncthreads();
  int excl = x - v + ws[wid];
  int dst = (b << 8) + t;
  if (dst < N) row_ptr[dst] = s + excl;
  __syncthreads();
  lh[t] = s + excl;        // reuse as cursor
  __syncthreads();
  for (int p = s + t; p < e2; p += 256) {
    int k = keys1[p] & 255;
    int pos = atomicAdd(&lh[k], 1);
    src_sorted[pos] = vals1[p];
  }
  if (b == 0 && t == 0) row_ptr[N] = Etot;
}

// --------------- layer-1 edge weights in CSR order (coalesced writes)
__global__ __launch_bounds__(256) void k_w1csr(const int* __restrict__ row_ptr,
                                               const int* __restrict__ src_sorted,
                                               const float* __restrict__ s_src,
                                               const float* __restrict__ s_dst,
                                               float4* __restrict__ w1s, int N) {
  int n = blockIdx.x * 4 + (threadIdx.x >> 6);
  if (n >= N) return;
  int lane = threadIdx.x & 63;
  float4 sd = *reinterpret_cast<const float4*>(s_dst + (size_t)n * 4);
  int beg = row_ptr[n], end = row_ptr[n + 1];
  for (int p = beg + lane; p < end; p += 64) {
    int s = src_sorted[p];
    float4 ss = *reinterpret_cast<const float4*>(s_src + (size_t)s * 4);
    float4 w;
    w.x = leaky_exp(ss.x + sd.x);
    w.y = leaky_exp(ss.y + sd.y);
    w.z = leaky_exp(ss.z + sd.z);
    w.w = leaky_exp(ss.w + sd.w);
    w1s[p] = w;
  }
}

// --------------- layer-2 edge weights in CSR order
__global__ __launch_bounds__(256) void k_w2csr(const int* __restrict__ row_ptr,
                                               const int* __restrict__ src_sorted,
                                               const float* __restrict__ s2s,
                                               const float* __restrict__ s2d,
                                               float* __restrict__ w2s, int N) {
  int n = blockIdx.x * 4 + (threadIdx.x >> 6);
  if (n >= N) return;
  int lane = threadIdx.x & 63;
  float sdn = s2d[n];
  int beg = row_ptr[n], end = row_ptr[n + 1];
  for (int p = beg + lane; p < end; p += 64) {
    w2s[p] = leaky_exp(s2s[src_sorted[p]] + sdn);
  }
}

// ---------------------------- layer-1 aggregation over x (bf16), 4 heads
__global__ __launch_bounds__(256) void k_aggx(const unsigned short* __restrict__ xb,
                                              const int* __restrict__ row_ptr,
                                              const int* __restrict__ src_sorted,
                                              const float4* __restrict__ w1s,
                                              unsigned short* __restrict__ avgxb,
                                              int N) {
  int n = blockIdx.x * 4 + (threadIdx.x >> 6);
  if (n >= N) return;
  int lane = threadIdx.x & 63;
  int beg = row_ptr[n], end = row_ptr[n + 1];
  float acc[4][2] = {};
  float wsum[4] = {};
  int p = beg;
  for (; p + 4 <= end; p += 4) {
    int s[4];
    float4 w[4];
    unsigned int pk[4];
#pragma unroll
    for (int j = 0; j < 4; j++) s[j] = src_sorted[p + j];
#pragma unroll
    for (int j = 0; j < 4; j++) w[j] = w1s[p + j];
#pragma unroll
    for (int j = 0; j < 4; j++)
      pk[j] = *reinterpret_cast<const unsigned int*>(xb + (size_t)s[j] * 128 + lane * 2);
#pragma unroll
    for (int j = 0; j < 4; j++) {
      float x0 = __uint_as_float(pk[j] << 16);
      float x1 = __uint_as_float(pk[j] & 0xFFFF0000u);
      acc[0][0] = fmaf(w[j].x, x0, acc[0][0]); acc[0][1] = fmaf(w[j].x, x1, acc[0][1]);
      acc[1][0] = fmaf(w[j].y, x0, acc[1][0]); acc[1][1] = fmaf(w[j].y, x1, acc[1][1]);
      acc[2][0] = fmaf(w[j].z, x0, acc[2][0]); acc[2][1] = fmaf(w[j].z, x1, acc[2][1]);
      acc[3][0] = fmaf(w[j].w, x0, acc[3][0]); acc[3][1] = fmaf(w[j].w, x1, acc[3][1]);
      wsum[0] += w[j].x; wsum[1] += w[j].y; wsum[2] += w[j].z; wsum[3] += w[j].w;
    }
  }
  for (; p < end; p++) {
    int s = src_sorted[p];
    float4 w = w1s[p];
    unsigned int pk = *reinterpret_cast<const unsigned int*>(xb + (size_t)s * 128 + lane * 2);
    float x0 = __uint_as_float(pk << 16);
    float x1 = __uint_as_float(pk & 0xFFFF0000u);
    acc[0][0] = fmaf(w.x, x0, acc[0][0]); acc[0][1] = fmaf(w.x, x1, acc[0][1]);
    acc[1][0] = fmaf(w.y, x0, acc[1][0]); acc[1][1] = fmaf(w.y, x1, acc[1][1]);
    acc[2][0] = fmaf(w.z, x0, acc[2][0]); acc[2][1] = fmaf(w.z, x1, acc[2][1]);
    acc[3][0] = fmaf(w.w, x0, acc[3][0]); acc[3][1] = fmaf(w.w, x1, acc[3][1]);
    wsum[0] += w.x; wsum[1] += w.y; wsum[2] += w.z; wsum[3] += w.w;
  }
#pragma unroll
  for (int h = 0; h < 4; h++) {
    float inv = 1.f / (wsum[h] + 1e-16f);
    unsigned int pk = ((unsigned int)f2b(acc[h][1] * inv) << 16) | f2b(acc[h][0] * inv);
    *reinterpret_cast<unsigned int*>(avgxb + (size_t)n * 512 + h * 128 + lane * 2) = pk;
  }
}

// -------------------- layer-2 aggregation (bf16 h2) + fused relu + out head
__global__ __launch_bounds__(256) void k_agg2(const unsigned short* __restrict__ h2b,
                                              const int* __restrict__ row_ptr,
                                              const int* __restrict__ src_sorted,
                                              const float* __restrict__ w2s,
                                              const float* __restrict__ bias,
                                              const float* __restrict__ Wout,
                                              const float* __restrict__ bout,
                                              float* __restrict__ logits, int N) {
  int n = blockIdx.x * 4 + (threadIdx.x >> 6);
  if (n >= N) return;
  int lane = threadIdx.x & 63;
  int beg = row_ptr[n], end = row_ptr[n + 1];
  float acc = 0.f, wsum = 0.f;
  int p = beg;
  for (; p + 8 <= end; p += 8) {
    int s[8];
    float w[8];
    unsigned short hv[8];
#pragma unroll
    for (int j = 0; j < 8; j++) s[j] = src_sorted[p + j];
#pragma unroll
    for (int j = 0; j < 8; j++) w[j] = w2s[p + j];
#pragma unroll
    for (int j = 0; j < 8; j++) hv[j] = h2b[(size_t)s[j] * 64 + lane];
#pragma unroll
    for (int j = 0; j < 8; j++) {
      acc = fmaf(w[j], b2f(hv[j]), acc);
      wsum += w[j];
    }
  }
  for (; p < end; p++) {
    float w = w2s[p];
    acc = fmaf(w, b2f(h2b[(size_t)src_sorted[p] * 64 + lane]), acc);
    wsum += w;
  }
  float o = fmaxf(acc / (wsum + 1e-16f) + bias[lane], 0.f);
  float v = o * Wout[lane];
#pragma unroll
  for (int off = 32; off; off >>= 1) v += __shfl_xor(v, off, 64);
  if (lane == 0) logits[n] = v + bout[0];
}

extern "C" void kernel_launch(void* const* d_in, const int* in_sizes, int n_in,
                              void* d_out, int out_size, void* d_ws, size_t ws_size,
                              hipStream_t stream) {
  const float* x      = (const float*)d_in[0];
  const int*   ei     = (const int*)d_in[1];
  const float* W1     = (const float*)d_in[2];
  const float* a_src1 = (const float*)d_in[3];
  const float* a_dst1 = (const float*)d_in[4];
  const float* b1     = (const float*)d_in[5];
  const float* W2     = (const float*)d_in[6];
  const float* a_src2 = (const float*)d_in[7];
  const float* a_dst2 = (const float*)d_in[8];
  const float* b2     = (const float*)d_in[9];
  const float* Wout   = (const float*)d_in[10];
  const float* bout   = (const float*)d_in[11];
  float* logits = (float*)d_out;

  const int HC1  = in_sizes[5];           // 256
  const int F_IN = in_sizes[2] / HC1;     // 128
  const int N    = in_sizes[0] / F_IN;    // 50000
  const int E    = in_sizes[1] / 2;       // 1.6M
  const int Etot = E + N;
  const int NBUCK = (N + 255) >> 8;       // 196 (<=256 supported)

  char* w = (char*)d_ws;
  auto alloc = [&](size_t bytes) {
    char* p = w;
    w += (bytes + 255) & ~(size_t)255;
    return p;
  };
  // region A: xb (bf16 x); dead after k_aggx
  char* regA = alloc((size_t)N * 128 * sizeof(unsigned short));  // 12.8 MB
  unsigned short* xb = (unsigned short*)regA;
  // region B: avgxb (bf16); dead after k_gh_mfma -> h2b at offset 0,
  // w2s at offset 25.6 MB.
  char* regB = alloc((size_t)N * 512 * sizeof(unsigned short));  // 51.2 MB
  unsigned short* avgxb = (unsigned short*)regB;
  unsigned short* h2b = (unsigned short*)regB;
  float* w2s = (float*)(regB + (size_t)N * 256 * sizeof(unsigned short));
  // region C (51.2 MB), time-multiplexed:
  //   phase 1: keys1 (6.6 MB) + vals1 (6.6 MB)      [sort, dead after k_sortB]
  //   phase 2: w1s (26.4 MB)                        [dead after k_aggx]
  //   phase 3: hact_hi (25.6 MB) + hact_lo (25.6 MB)
  char* regC = alloc((size_t)N * 256 * 4);                       // 51.2 MB
  int* keys1 = (int*)regC;
  int* vals1 = (int*)(regC + (size_t)Etot * 4 + 256);
  float4* w1s = (float4*)regC;
  unsigned short* hact_hi = (unsigned short*)regC;
  unsigned short* hact_lo = (unsigned short*)(regC + (size_t)N * 256 * sizeof(unsigned short));
  float* s_src1  = (float*)alloc((size_t)N * 4 * 4);
  float* s_dst1  = (float*)alloc((size_t)N * 4 * 4);
  float* s2_src  = (float*)alloc((size_t)N * 4);
  float* s2_dst  = (float*)alloc((size_t)N * 4);
  float* va      = (float*)alloc(128 * 8 * 4);
  unsigned short* W1h = (unsigned short*)alloc(4096 * 8 * 2);    // 64 KB
  unsigned short* W1l = (unsigned short*)alloc(4096 * 8 * 2);
  unsigned short* W2h = (unsigned short*)alloc(2048 * 8 * 2);    // 32 KB
  unsigned short* W2l = (unsigned short*)alloc(2048 * 8 * 2);
  int* row_ptr   = (int*)alloc((size_t)(N + 1) * 4);
  int* src_sorted= (int*)alloc((size_t)Etot * 4);
  int* ghist     = (int*)alloc(256 * 4);
  int* bstart    = (int*)alloc(260 * 4);
  int* gcur      = (int*)alloc(256 * 4);

  hipMemsetAsync(ghist, 0, 256 * 4, stream);

  // ---- prep: W hi/lo swizzles + vproj ----
  k_prep<<<28, 256, 0, stream>>>(W1, W2, a_src1, a_dst1, W1h, W1l, W2h, W2l, va);
  k_scores_x<<<(N + 3) / 4, 256, 0, stream>>>(x, va, s_src1, s_dst1, xb, N);

  // ---- CSR build via MSD bucket sort ----
  const int gsort = (Etot + 2047) / 2048;
  k_histA<<<gsort, 256, 0, stream>>>(ei, E, Etot, ghist);
  k_scan196<<<1, 256, 0, stream>>>(ghist, bstart, gcur, NBUCK, Etot);
  k_scatterA<<<gsort, 256, 0, stream>>>(ei, E, Etot, gcur, keys1, vals1);
  k_sortB<<<NBUCK, 256, 0, stream>>>(keys1, vals1, bstart, src_sorted, row_ptr, N, Etot);

  // ---- layer 1 (h1 never materialized) ----
  k_w1csr<<<(N + 3) / 4, 256, 0, stream>>>(row_ptr, src_sorted, s_src1, s_dst1, w1s, N);
  k_aggx<<<(N + 3) / 4, 256, 0, stream>>>(xb, row_ptr, src_sorted, w1s, avgxb, N);
  dim3 gh((N + 63) / 64, 1, 4);
  k_gh_mfma<<<gh, 256, 0, stream>>>(avgxb, W1h, W1l, b1, hact_hi, hact_lo, N);

  // ---- layer 2 ----
  k_g2_mfma<<<(N + 63) / 64, 256, 0, stream>>>(hact_hi, hact_lo, W2h, W2l, h2b, N);
  k_scores2<<<(N + 3) / 4, 256, 0, stream>>>(h2b, a_src2, a_dst2, s2_src, s2_dst, N);
  k_w2csr<<<(N + 3) / 4, 256, 0, stream>>>(row_ptr, src_sorted, s2_src, s2_dst, w2s, N);
  k_agg2<<<(N + 3) / 4, 256, 0, stream>>>(h2b, row_ptr, src_sorted, w2s,
                                          b2, Wout, bout, logits, N);
}

// Round 12
// 420.037 us; speedup vs baseline: 1.5501x; 1.0125x over previous
//
#include <hip/hip_runtime.h>
#include <hip/hip_bf16.h>

#define NEG_SLOPE 0.2f

using bf16x8 = __attribute__((ext_vector_type(8))) short;  // 8 bf16 (4 VGPRs)
using f32x4  = __attribute__((ext_vector_type(4))) float;  // 4 fp32 acc

// bf16 helpers: store with RNE, load via bit-shift (exact)
__device__ __forceinline__ unsigned short f2b(float f) {
  unsigned int u = __float_as_uint(f);
  unsigned int r = (u + 0x7FFFu + ((u >> 16) & 1u)) >> 16;
  return (unsigned short)r;
}
__device__ __forceinline__ float b2f(unsigned short v) {
  return __uint_as_float(((unsigned int)v) << 16);
}
__device__ __forceinline__ float leaky_exp(float e) {
  e = e > 0.f ? e : NEG_SLOPE * e;
  return __expf(e);
}

// ------- fused prep: W1/W2 hi-lo swizzle + vproj + ghist zero (29 blocks) ---
__global__ void k_prep(const float* __restrict__ W1,
                       const float* __restrict__ W2,
                       const float* __restrict__ a_src1,
                       const float* __restrict__ a_dst1,
                       unsigned short* __restrict__ W1h,
                       unsigned short* __restrict__ W1l,
                       unsigned short* __restrict__ W2h,
                       unsigned short* __restrict__ W2l,
                       float* __restrict__ va,
                       int* __restrict__ ghist) {
  int b = blockIdx.x;
  int t = threadIdx.x;
  if (b < 16) {                                  // --- prepW1 (4096 frags)
    int g = b * 256 + t;
    int l = g & 63, tt = (g >> 6) & 3, kc = (g >> 8) & 3, h = (g >> 10) & 3;
    int n = h * 64 + tt * 16 + (l & 15);
    int kbase = kc * 32 + (l >> 4) * 8;
    size_t base = ((((size_t)h * 4 + kc) * 4 + tt) * 64 + l) * 8;
#pragma unroll
    for (int j = 0; j < 8; j++) {
      float v = W1[(size_t)(kbase + j) * 256 + n];
      unsigned short hi = f2b(v);
      W1h[base + j] = hi;
      W1l[base + j] = f2b(v - b2f(hi));
    }
  } else if (b < 24) {                           // --- prepW2 (2048 frags)
    int g = (b - 16) * 256 + t;
    int l = g & 63, tt = (g >> 6) & 3, kc = (g >> 8) & 7;
    int n = tt * 16 + (l & 15);
    int kbase = kc * 32 + (l >> 4) * 8;
    size_t base = (((size_t)kc * 4 + tt) * 64 + l) * 8;
#pragma unroll
    for (int j = 0; j < 8; j++) {
      float v = W2[(size_t)(kbase + j) * 64 + n];
      unsigned short hi = f2b(v);
      W2h[base + j] = hi;
      W2l[base + j] = f2b(v - b2f(hi));
    }
  } else if (b < 28) {                           // --- vproj (1024 entries)
    int g = (b - 24) * 256 + t;
    int k = g >> 3, j = g & 7;
    int h = j & 3;
    const float* a = (j < 4) ? a_src1 : a_dst1;
    float s = 0.f;
    for (int c = 0; c < 64; c++) s += W1[(size_t)k * 256 + h * 64 + c] * a[h * 64 + c];
    va[k * 8 + j] = s;
  } else {                                       // --- ghist zero
    ghist[t] = 0;
  }
}

// ------------- layer-1 GEMM via MFMA: hact = relu(avgxb @ (W1h+W1l) + b1)
__global__ __launch_bounds__(256) void k_gh_mfma(const unsigned short* __restrict__ Ab,
                                                 const unsigned short* __restrict__ W1h,
                                                 const unsigned short* __restrict__ W1l,
                                                 const float* __restrict__ b1,
                                                 unsigned short* __restrict__ hact_hi,
                                                 unsigned short* __restrict__ hact_lo,
                                                 int M) {
  const int w = threadIdx.x >> 6, l = threadIdx.x & 63;
  const int h = blockIdx.z;
  const int rowA = blockIdx.x * 64 + w * 16 + (l & 15);
  const int rA = rowA < M ? rowA : M - 1;
  const int kg = l >> 4;
  const unsigned short* Aptr = Ab + (size_t)rA * 512 + h * 128 + kg * 8;
  f32x4 acc[4] = {{0.f, 0.f, 0.f, 0.f}, {0.f, 0.f, 0.f, 0.f},
                  {0.f, 0.f, 0.f, 0.f}, {0.f, 0.f, 0.f, 0.f}};
#pragma unroll
  for (int kc = 0; kc < 4; kc++) {
    bf16x8 a = *reinterpret_cast<const bf16x8*>(Aptr + kc * 32);
#pragma unroll
    for (int t = 0; t < 4; t++) {
      size_t base = ((((size_t)h * 4 + kc) * 4 + t) * 64 + l) * 8;
      bf16x8 bh = *reinterpret_cast<const bf16x8*>(W1h + base);
      bf16x8 bl = *reinterpret_cast<const bf16x8*>(W1l + base);
      acc[t] = __builtin_amdgcn_mfma_f32_16x16x32_bf16(a, bh, acc[t], 0, 0, 0);
      acc[t] = __builtin_amdgcn_mfma_f32_16x16x32_bf16(a, bl, acc[t], 0, 0, 0);
    }
  }
  const int orow0 = blockIdx.x * 64 + w * 16 + (l >> 4) * 4;
  const int col16 = l & 15;
#pragma unroll
  for (int t = 0; t < 4; t++) {
    int col = h * 64 + t * 16 + col16;
    float bb = b1[col];
#pragma unroll
    for (int r = 0; r < 4; r++) {
      int row = orow0 + r;
      if (row < M) {
        float v = fmaxf(acc[t][r] + bb, 0.f);
        unsigned short hi = f2b(v);
        hact_hi[(size_t)row * 256 + col] = hi;
        hact_lo[(size_t)row * 256 + col] = f2b(v - b2f(hi));
      }
    }
  }
}

// ------------- layer-2 GEMM via MFMA: h2b = (Ah+Al) @ (W2h+W2l), K=256
__global__ __launch_bounds__(256) void k_g2_mfma(const unsigned short* __restrict__ Ahi,
                                                 const unsigned short* __restrict__ Alo,
                                                 const unsigned short* __restrict__ W2h,
                                                 const unsigned short* __restrict__ W2l,
                                                 unsigned short* __restrict__ h2b,
                                                 int M) {
  const int w = threadIdx.x >> 6, l = threadIdx.x & 63;
  const int rowA = blockIdx.x * 64 + w * 16 + (l & 15);
  const int rA = rowA < M ? rowA : M - 1;
  const int kg = l >> 4;
  const unsigned short* Ah = Ahi + (size_t)rA * 256 + kg * 8;
  const unsigned short* Al = Alo + (size_t)rA * 256 + kg * 8;
  f32x4 acc[4] = {{0.f, 0.f, 0.f, 0.f}, {0.f, 0.f, 0.f, 0.f},
                  {0.f, 0.f, 0.f, 0.f}, {0.f, 0.f, 0.f, 0.f}};
#pragma unroll
  for (int kc = 0; kc < 8; kc++) {
    bf16x8 ah = *reinterpret_cast<const bf16x8*>(Ah + kc * 32);
    bf16x8 al = *reinterpret_cast<const bf16x8*>(Al + kc * 32);
#pragma unroll
    for (int t = 0; t < 4; t++) {
      size_t base = (((size_t)kc * 4 + t) * 64 + l) * 8;
      bf16x8 bh = *reinterpret_cast<const bf16x8*>(W2h + base);
      bf16x8 bl = *reinterpret_cast<const bf16x8*>(W2l + base);
      acc[t] = __builtin_amdgcn_mfma_f32_16x16x32_bf16(ah, bh, acc[t], 0, 0, 0);
      acc[t] = __builtin_amdgcn_mfma_f32_16x16x32_bf16(ah, bl, acc[t], 0, 0, 0);
      acc[t] = __builtin_amdgcn_mfma_f32_16x16x32_bf16(al, bh, acc[t], 0, 0, 0);
    }
  }
  const int orow0 = blockIdx.x * 64 + w * 16 + (l >> 4) * 4;
  const int col16 = l & 15;
#pragma unroll
  for (int t = 0; t < 4; t++) {
    int col = t * 16 + col16;
#pragma unroll
    for (int r = 0; r < 4; r++) {
      int row = orow0 + r;
      if (row < M) h2b[(size_t)row * 64 + col] = f2b(acc[t][r]);
    }
  }
}

// --- scores from x + fused bf16 cast + (tail blocks) coarse histogram -------
__global__ __launch_bounds__(256) void k_sxh(const float* __restrict__ x,
                                             const float* __restrict__ va,
                                             float* __restrict__ s_src,
                                             float* __restrict__ s_dst,
                                             unsigned short* __restrict__ xb,
                                             int N, int nsx,
                                             const int* __restrict__ ei,
                                             int E, int Etot,
                                             int* __restrict__ ghist) {
  __shared__ int lh[256];
  if (blockIdx.x >= nsx) {                 // ---- histogram part
    int t = threadIdx.x;
    lh[t] = 0;
    __syncthreads();
    int base = ((blockIdx.x - nsx) * 256 + t) * 8;
#pragma unroll
    for (int j = 0; j < 8; j++) {
      int e = base + j;
      if (e < Etot) {
        int dst = (e < E) ? ei[E + e] : (e - E);
        atomicAdd(&lh[dst >> 8], 1);
      }
    }
    __syncthreads();
    if (lh[t]) atomicAdd(&ghist[t], lh[t]);
    return;
  }
  int n = blockIdx.x * 4 + (threadIdx.x >> 6);
  if (n >= N) return;
  int lane = threadIdx.x & 63;
  float x0 = x[(size_t)n * 128 + lane];
  float x1 = x[(size_t)n * 128 + 64 + lane];
  xb[(size_t)n * 128 + lane] = f2b(x0);
  xb[(size_t)n * 128 + 64 + lane] = f2b(x1);
  float4 vs0 = *reinterpret_cast<const float4*>(va + lane * 8);
  float4 vd0 = *reinterpret_cast<const float4*>(va + lane * 8 + 4);
  float4 vs1 = *reinterpret_cast<const float4*>(va + (lane + 64) * 8);
  float4 vd1 = *reinterpret_cast<const float4*>(va + (lane + 64) * 8 + 4);
  float rs0 = x0 * vs0.x + x1 * vs1.x, rs1 = x0 * vs0.y + x1 * vs1.y;
  float rs2 = x0 * vs0.z + x1 * vs1.z, rs3 = x0 * vs0.w + x1 * vs1.w;
  float rd0 = x0 * vd0.x + x1 * vd1.x, rd1 = x0 * vd0.y + x1 * vd1.y;
  float rd2 = x0 * vd0.z + x1 * vd1.z, rd3 = x0 * vd0.w + x1 * vd1.w;
#pragma unroll
  for (int off = 32; off; off >>= 1) {
    rs0 += __shfl_xor(rs0, off, 64); rs1 += __shfl_xor(rs1, off, 64);
    rs2 += __shfl_xor(rs2, off, 64); rs3 += __shfl_xor(rs3, off, 64);
    rd0 += __shfl_xor(rd0, off, 64); rd1 += __shfl_xor(rd1, off, 64);
    rd2 += __shfl_xor(rd2, off, 64); rd3 += __shfl_xor(rd3, off, 64);
  }
  if (lane == 0) {
    float4 ss = {rs0, rs1, rs2, rs3};
    float4 dd = {rd0, rd1, rd2, rd3};
    *reinterpret_cast<float4*>(s_src + (size_t)n * 4) = ss;
    *reinterpret_cast<float4*>(s_dst + (size_t)n * 4) = dd;
  }
}

// ------------------------------------------- scores for layer 2 (bf16 input)
__global__ __launch_bounds__(256) void k_scores2(const unsigned short* __restrict__ h2b,
                                                 const float* __restrict__ a_src,
                                                 const float* __restrict__ a_dst,
                                                 float* __restrict__ s_src,
                                                 float* __restrict__ s_dst,
                                                 int N) {
  int n = blockIdx.x * 4 + (threadIdx.x >> 6);
  if (n >= N) return;
  int lane = threadIdx.x & 63;
  float hv = b2f(h2b[(size_t)n * 64 + lane]);
  float sv = hv * a_src[lane];
  float dv = hv * a_dst[lane];
#pragma unroll
  for (int off = 32; off; off >>= 1) {
    sv += __shfl_xor(sv, off, 64);
    dv += __shfl_xor(dv, off, 64);
  }
  if (lane == 0) {
    s_src[n] = sv;
    s_dst[n] = dv;
  }
}

// =================== MSD bucket sort CSR build ==============================
// scan 196 bucket counts -> bucketStart[0..196], gcursor
__global__ __launch_bounds__(256) void k_scan196(const int* __restrict__ ghist,
                                                 int* __restrict__ bstart,
                                                 int* __restrict__ gcur,
                                                 int nbuck, int Etot) {
  __shared__ int ws[4];
  int t = threadIdx.x;
  int lane = t & 63, wid = t >> 6;
  int v = (t < nbuck) ? ghist[t] : 0;
  int x = v;
#pragma unroll
  for (int off = 1; off < 64; off <<= 1) {
    int y = __shfl_up(x, off, 64);
    if (lane >= off) x += y;
  }
  if (lane == 63) ws[wid] = x;
  __syncthreads();
  if (t == 0) {
    int a0 = ws[0], a1 = ws[1], a2 = ws[2];
    ws[0] = 0; ws[1] = a0; ws[2] = a0 + a1; ws[3] = a0 + a1 + a2;
  }
  __syncthreads();
  int excl = x - v + ws[wid];
  if (t < nbuck) {
    bstart[t] = excl;
    gcur[t] = excl;
  }
  if (t == 0) bstart[nbuck] = Etot;
}

// scatter into coarse buckets: one returning atomic per (block,bucket).
__global__ void k_scatterA(const int* __restrict__ ei, int E, int Etot,
                           int* __restrict__ gcur,
                           int* __restrict__ keys1,
                           int* __restrict__ vals1) {
  __shared__ int lh[256];
  int t = threadIdx.x;
  lh[t] = 0;
  __syncthreads();
  int base = (blockIdx.x * 256 + t) * 8;
  int dsts[8], srcs[8];
#pragma unroll
  for (int j = 0; j < 8; j++) {
    int e = base + j;
    if (e < Etot) {
      int d, s;
      if (e < E) { d = ei[E + e]; s = ei[e]; }
      else       { d = s = e - E; }
      dsts[j] = d; srcs[j] = s;
      atomicAdd(&lh[d >> 8], 1);
    } else dsts[j] = -1;
  }
  __syncthreads();
  {
    int c = lh[t];
    lh[t] = c ? atomicAdd(&gcur[t], c) : 0;   // reserve contiguous range
  }
  __syncthreads();
#pragma unroll
  for (int j = 0; j < 8; j++) {
    if (dsts[j] >= 0) {
      int pos = atomicAdd(&lh[dsts[j] >> 8], 1);  // LDS cursor -> global pos
      keys1[pos] = dsts[j];
      vals1[pos] = srcs[j];
    }
  }
}

// Pass B: per-bucket LDS counting sort on dst&255; emits src_sorted + row_ptr.
__global__ __launch_bounds__(256) void k_sortB(const int* __restrict__ keys1,
                                               const int* __restrict__ vals1,
                                               const int* __restrict__ bstart,
                                               int* __restrict__ src_sorted,
                                               int* __restrict__ row_ptr,
                                               int N, int Etot) {
  __shared__ int lh[256];
  __shared__ int ws[4];
  int b = blockIdx.x;
  int t = threadIdx.x;
  int lane = t & 63, wid = t >> 6;
  int s = bstart[b], e2 = bstart[b + 1];
  lh[t] = 0;
  __syncthreads();
  for (int p = s + t; p < e2; p += 256)
    atomicAdd(&lh[keys1[p] & 255], 1);
  __syncthreads();
  int v = lh[t];
  int x = v;
#pragma unroll
  for (int off = 1; off < 64; off <<= 1) {
    int y = __shfl_up(x, off, 64);
    if (lane >= off) x += y;
  }
  if (lane == 63) ws[wid] = x;
  __syncthreads();
  if (t == 0) {
    int a0 = ws[0], a1 = ws[1], a2 = ws[2];
    ws[0] = 0; ws[1] = a0; ws[2] = a0 + a1; ws[3] = a0 + a1 + a2;
  }
  __syncthreads();
  int excl = x - v + ws[wid];
  int dst = (b << 8) + t;
  if (dst < N) row_ptr[dst] = s + excl;
  __syncthreads();
  lh[t] = s + excl;        // reuse as cursor
  __syncthreads();
  for (int p = s + t; p < e2; p += 256) {
    int k = keys1[p] & 255;
    int pos = atomicAdd(&lh[k], 1);
    src_sorted[pos] = vals1[p];
  }
  if (b == 0 && t == 0) row_ptr[N] = Etot;
}

// --------- layer-1 edge weights, PRE-NORMALIZED (w' = w / (sum w + 1e-16))
// wave per node; raw w cached in regs for first 4 strips (deg<=256 typical),
// rare overflow strips round-trip through w1s.
__global__ __launch_bounds__(256) void k_w1n(const int* __restrict__ row_ptr,
                                             const int* __restrict__ src_sorted,
                                             const float* __restrict__ s_src,
                                             const float* __restrict__ s_dst,
                                             float4* __restrict__ w1s, int N) {
  int n = blockIdx.x * 4 + (threadIdx.x >> 6);
  if (n >= N) return;
  int lane = threadIdx.x & 63;
  float4 sd = *reinterpret_cast<const float4*>(s_dst + (size_t)n * 4);
  int beg = row_ptr[n], end = row_ptr[n + 1];
  float4 wreg[4];
  float sx = 0.f, sy = 0.f, sz = 0.f, sw = 0.f;
  int i = 0;
  for (int p = beg + lane; p < end; p += 64, i++) {
    int s = src_sorted[p];
    float4 ss = *reinterpret_cast<const float4*>(s_src + (size_t)s * 4);
    float4 w;
    w.x = leaky_exp(ss.x + sd.x);
    w.y = leaky_exp(ss.y + sd.y);
    w.z = leaky_exp(ss.z + sd.z);
    w.w = leaky_exp(ss.w + sd.w);
    if (i < 4) wreg[i] = w; else w1s[p] = w;
    sx += w.x; sy += w.y; sz += w.z; sw += w.w;
  }
#pragma unroll
  for (int off = 32; off; off >>= 1) {
    sx += __shfl_xor(sx, off, 64); sy += __shfl_xor(sy, off, 64);
    sz += __shfl_xor(sz, off, 64); sw += __shfl_xor(sw, off, 64);
  }
  float ix = 1.f / (sx + 1e-16f), iy = 1.f / (sy + 1e-16f);
  float iz = 1.f / (sz + 1e-16f), iw = 1.f / (sw + 1e-16f);
  i = 0;
  for (int p = beg + lane; p < end; p += 64, i++) {
    float4 w = (i < 4) ? wreg[i] : w1s[p];
    w.x *= ix; w.y *= iy; w.z *= iz; w.w *= iw;
    w1s[p] = w;
  }
}

// --------- layer-2 edge weights, PRE-NORMALIZED
__global__ __launch_bounds__(256) void k_w2n(const int* __restrict__ row_ptr,
                                             const int* __restrict__ src_sorted,
                                             const float* __restrict__ s2s,
                                             const float* __restrict__ s2d,
                                             float* __restrict__ w2s, int N) {
  int n = blockIdx.x * 4 + (threadIdx.x >> 6);
  if (n >= N) return;
  int lane = threadIdx.x & 63;
  float sdn = s2d[n];
  int beg = row_ptr[n], end = row_ptr[n + 1];
  float wreg[4];
  float sum = 0.f;
  int i = 0;
  for (int p = beg + lane; p < end; p += 64, i++) {
    float w = leaky_exp(s2s[src_sorted[p]] + sdn);
    if (i < 4) wreg[i] = w; else w2s[p] = w;
    sum += w;
  }
#pragma unroll
  for (int off = 32; off; off >>= 1) sum += __shfl_xor(sum, off, 64);
  float inv = 1.f / (sum + 1e-16f);
  i = 0;
  for (int p = beg + lane; p < end; p += 64, i++) {
    float w = (i < 4) ? wreg[i] : w2s[p];
    w2s[p] = w * inv;
  }
}

// ------- layer-1 aggregation over x (bf16), 4 heads; normalized w, unroll 8
__global__ __launch_bounds__(256) void k_aggx(const unsigned short* __restrict__ xb,
                                              const int* __restrict__ row_ptr,
                                              const int* __restrict__ src_sorted,
                                              const float4* __restrict__ w1s,
                                              unsigned short* __restrict__ avgxb,
                                              int N) {
  int n = blockIdx.x * 4 + (threadIdx.x >> 6);
  if (n >= N) return;
  int lane = threadIdx.x & 63;
  int beg = row_ptr[n], end = row_ptr[n + 1];
  float acc[4][2] = {};
  int p = beg;
  for (; p + 8 <= end; p += 8) {
    int s[8];
    float4 w[8];
    unsigned int pk[8];
#pragma unroll
    for (int j = 0; j < 8; j++) s[j] = src_sorted[p + j];
#pragma unroll
    for (int j = 0; j < 8; j++) w[j] = w1s[p + j];
#pragma unroll
    for (int j = 0; j < 8; j++)
      pk[j] = *reinterpret_cast<const unsigned int*>(xb + (size_t)s[j] * 128 + lane * 2);
#pragma unroll
    for (int j = 0; j < 8; j++) {
      float x0 = __uint_as_float(pk[j] << 16);
      float x1 = __uint_as_float(pk[j] & 0xFFFF0000u);
      acc[0][0] = fmaf(w[j].x, x0, acc[0][0]); acc[0][1] = fmaf(w[j].x, x1, acc[0][1]);
      acc[1][0] = fmaf(w[j].y, x0, acc[1][0]); acc[1][1] = fmaf(w[j].y, x1, acc[1][1]);
      acc[2][0] = fmaf(w[j].z, x0, acc[2][0]); acc[2][1] = fmaf(w[j].z, x1, acc[2][1]);
      acc[3][0] = fmaf(w[j].w, x0, acc[3][0]); acc[3][1] = fmaf(w[j].w, x1, acc[3][1]);
    }
  }
  for (; p < end; p++) {
    int s = src_sorted[p];
    float4 w = w1s[p];
    unsigned int pk = *reinterpret_cast<const unsigned int*>(xb + (size_t)s * 128 + lane * 2);
    float x0 = __uint_as_float(pk << 16);
    float x1 = __uint_as_float(pk & 0xFFFF0000u);
    acc[0][0] = fmaf(w.x, x0, acc[0][0]); acc[0][1] = fmaf(w.x, x1, acc[0][1]);
    acc[1][0] = fmaf(w.y, x0, acc[1][0]); acc[1][1] = fmaf(w.y, x1, acc[1][1]);
    acc[2][0] = fmaf(w.z, x0, acc[2][0]); acc[2][1] = fmaf(w.z, x1, acc[2][1]);
    acc[3][0] = fmaf(w.w, x0, acc[3][0]); acc[3][1] = fmaf(w.w, x1, acc[3][1]);
  }
#pragma unroll
  for (int h = 0; h < 4; h++) {
    unsigned int pk = ((unsigned int)f2b(acc[h][1]) << 16) | f2b(acc[h][0]);
    *reinterpret_cast<unsigned int*>(avgxb + (size_t)n * 512 + h * 128 + lane * 2) = pk;
  }
}

// --- layer-2 aggregation (bf16 h2, normalized w2) + fused relu + out head
__global__ __launch_bounds__(256) void k_agg2(const unsigned short* __restrict__ h2b,
                                              const int* __restrict__ row_ptr,
                                              const int* __restrict__ src_sorted,
                                              const float* __restrict__ w2s,
                                              const float* __restrict__ bias,
                                              const float* __restrict__ Wout,
                                              const float* __restrict__ bout,
                                              float* __restrict__ logits, int N) {
  int n = blockIdx.x * 4 + (threadIdx.x >> 6);
  if (n >= N) return;
  int lane = threadIdx.x & 63;
  int beg = row_ptr[n], end = row_ptr[n + 1];
  float acc = 0.f;
  int p = beg;
  for (; p + 8 <= end; p += 8) {
    int s[8];
    float w[8];
    unsigned short hv[8];
#pragma unroll
    for (int j = 0; j < 8; j++) s[j] = src_sorted[p + j];
#pragma unroll
    for (int j = 0; j < 8; j++) w[j] = w2s[p + j];
#pragma unroll
    for (int j = 0; j < 8; j++) hv[j] = h2b[(size_t)s[j] * 64 + lane];
#pragma unroll
    for (int j = 0; j < 8; j++) acc = fmaf(w[j], b2f(hv[j]), acc);
  }
  for (; p < end; p++)
    acc = fmaf(w2s[p], b2f(h2b[(size_t)src_sorted[p] * 64 + lane]), acc);
  float o = fmaxf(acc + bias[lane], 0.f);
  float v = o * Wout[lane];
#pragma unroll
  for (int off = 32; off; off >>= 1) v += __shfl_xor(v, off, 64);
  if (lane == 0) logits[n] = v + bout[0];
}

extern "C" void kernel_launch(void* const* d_in, const int* in_sizes, int n_in,
                              void* d_out, int out_size, void* d_ws, size_t ws_size,
                              hipStream_t stream) {
  const float* x      = (const float*)d_in[0];
  const int*   ei     = (const int*)d_in[1];
  const float* W1     = (const float*)d_in[2];
  const float* a_src1 = (const float*)d_in[3];
  const float* a_dst1 = (const float*)d_in[4];
  const float* b1     = (const float*)d_in[5];
  const float* W2     = (const float*)d_in[6];
  const float* a_src2 = (const float*)d_in[7];
  const float* a_dst2 = (const float*)d_in[8];
  const float* b2     = (const float*)d_in[9];
  const float* Wout   = (const float*)d_in[10];
  const float* bout   = (const float*)d_in[11];
  float* logits = (float*)d_out;

  const int HC1  = in_sizes[5];           // 256
  const int F_IN = in_sizes[2] / HC1;     // 128
  const int N    = in_sizes[0] / F_IN;    // 50000
  const int E    = in_sizes[1] / 2;       // 1.6M
  const int Etot = E + N;
  const int NBUCK = (N + 255) >> 8;       // 196 (<=256 supported)

  char* w = (char*)d_ws;
  auto alloc = [&](size_t bytes) {
    char* p = w;
    w += (bytes + 255) & ~(size_t)255;
    return p;
  };
  // region A: xb (bf16 x); dead after k_aggx
  char* regA = alloc((size_t)N * 128 * sizeof(unsigned short));  // 12.8 MB
  unsigned short* xb = (unsigned short*)regA;
  // region B: avgxb (bf16); dead after k_gh_mfma -> h2b at offset 0,
  // w2s at offset 25.6 MB.
  char* regB = alloc((size_t)N * 512 * sizeof(unsigned short));  // 51.2 MB
  unsigned short* avgxb = (unsigned short*)regB;
  unsigned short* h2b = (unsigned short*)regB;
  float* w2s = (float*)(regB + (size_t)N * 256 * sizeof(unsigned short));
  // region C (51.2 MB), time-multiplexed:
  //   phase 1: keys1 (6.6 MB) + vals1 (6.6 MB)      [sort, dead after k_sortB]
  //   phase 2: w1s (26.4 MB)                        [dead after k_aggx]
  //   phase 3: hact_hi (25.6 MB) + hact_lo (25.6 MB)
  char* regC = alloc((size_t)N * 256 * 4);                       // 51.2 MB
  int* keys1 = (int*)regC;
  int* vals1 = (int*)(regC + (size_t)Etot * 4 + 256);
  float4* w1s = (float4*)regC;
  unsigned short* hact_hi = (unsigned short*)regC;
  unsigned short* hact_lo = (unsigned short*)(regC + (size_t)N * 256 * sizeof(unsigned short));
  float* s_src1  = (float*)alloc((size_t)N * 4 * 4);
  float* s_dst1  = (float*)alloc((size_t)N * 4 * 4);
  float* s2_src  = (float*)alloc((size_t)N * 4);
  float* s2_dst  = (float*)alloc((size_t)N * 4);
  float* va      = (float*)alloc(128 * 8 * 4);
  unsigned short* W1h = (unsigned short*)alloc(4096 * 8 * 2);    // 64 KB
  unsigned short* W1l = (unsigned short*)alloc(4096 * 8 * 2);
  unsigned short* W2h = (unsigned short*)alloc(2048 * 8 * 2);    // 32 KB
  unsigned short* W2l = (unsigned short*)alloc(2048 * 8 * 2);
  int* row_ptr   = (int*)alloc((size_t)(N + 1) * 4);
  int* src_sorted= (int*)alloc((size_t)Etot * 4);
  int* ghist     = (int*)alloc(256 * 4);
  int* bstart    = (int*)alloc(260 * 4);
  int* gcur      = (int*)alloc(256 * 4);

  // ---- prep: W hi/lo swizzles + vproj + ghist zero ----
  k_prep<<<29, 256, 0, stream>>>(W1, W2, a_src1, a_dst1, W1h, W1l, W2h, W2l,
                                 va, ghist);

  // ---- scores_x (+cast) fused with coarse histogram ----
  const int nsx = (N + 3) / 4;
  const int gsort = (Etot + 2047) / 2048;
  k_sxh<<<nsx + gsort, 256, 0, stream>>>(x, va, s_src1, s_dst1, xb, N, nsx,
                                         ei, E, Etot, ghist);

  // ---- CSR build via MSD bucket sort ----
  k_scan196<<<1, 256, 0, stream>>>(ghist, bstart, gcur, NBUCK, Etot);
  k_scatterA<<<gsort, 256, 0, stream>>>(ei, E, Etot, gcur, keys1, vals1);
  k_sortB<<<NBUCK, 256, 0, stream>>>(keys1, vals1, bstart, src_sorted, row_ptr, N, Etot);

  // ---- layer 1 (h1 never materialized) ----
  k_w1n<<<(N + 3) / 4, 256, 0, stream>>>(row_ptr, src_sorted, s_src1, s_dst1, w1s, N);
  k_aggx<<<(N + 3) / 4, 256, 0, stream>>>(xb, row_ptr, src_sorted, w1s, avgxb, N);
  dim3 gh((N + 63) / 64, 1, 4);
  k_gh_mfma<<<gh, 256, 0, stream>>>(avgxb, W1h, W1l, b1, hact_hi, hact_lo, N);

  // ---- layer 2 ----
  k_g2_mfma<<<(N + 63) / 64, 256, 0, stream>>>(hact_hi, hact_lo, W2h, W2l, h2b, N);
  k_scores2<<<(N + 3) / 4, 256, 0, stream>>>(h2b, a_src2, a_dst2, s2_src, s2_dst, N);
  k_w2n<<<(N + 3) / 4, 256, 0, stream>>>(row_ptr, src_sorted, s2_src, s2_dst, w2s, N);
  k_agg2<<<(N + 3) / 4, 256, 0, stream>>>(h2b, row_ptr, src_sorted, w2s,
                                          b2, Wout, bout, logits, N);
}

// Round 15
// 372.639 us; speedup vs baseline: 1.7472x; 1.1272x over previous
//
#include <hip/hip_runtime.h>
#include <hip/hip_bf16.h>

#define NEG_SLOPE 0.2f

using bf16x8 = __attribute__((ext_vector_type(8))) short;  // 8 bf16 (4 VGPRs)
using f32x4  = __attribute__((ext_vector_type(4))) float;  // 4 fp32 acc

// bf16 helpers: store with RNE, load via bit-shift (exact)
__device__ __forceinline__ unsigned short f2b(float f) {
  unsigned int u = __float_as_uint(f);
  unsigned int r = (u + 0x7FFFu + ((u >> 16) & 1u)) >> 16;
  return (unsigned short)r;
}
__device__ __forceinline__ float b2f(unsigned short v) {
  return __uint_as_float(((unsigned int)v) << 16);
}
__device__ __forceinline__ float leaky_exp(float e) {
  e = e > 0.f ? e : NEG_SLOPE * e;
  return __expf(e);
}

// ------- fused prep: W1/W2 hi-lo swizzle + vproj + ghist zero (29 blocks) ---
__global__ void k_prep(const float* __restrict__ W1,
                       const float* __restrict__ W2,
                       const float* __restrict__ a_src1,
                       const float* __restrict__ a_dst1,
                       unsigned short* __restrict__ W1h,
                       unsigned short* __restrict__ W1l,
                       unsigned short* __restrict__ W2h,
                       unsigned short* __restrict__ W2l,
                       float* __restrict__ va,
                       int* __restrict__ ghist) {
  int b = blockIdx.x;
  int t = threadIdx.x;
  if (b < 16) {                                  // --- prepW1 (4096 frags)
    int g = b * 256 + t;
    int l = g & 63, tt = (g >> 6) & 3, kc = (g >> 8) & 3, h = (g >> 10) & 3;
    int n = h * 64 + tt * 16 + (l & 15);
    int kbase = kc * 32 + (l >> 4) * 8;
    size_t base = ((((size_t)h * 4 + kc) * 4 + tt) * 64 + l) * 8;
#pragma unroll
    for (int j = 0; j < 8; j++) {
      float v = W1[(size_t)(kbase + j) * 256 + n];
      unsigned short hi = f2b(v);
      W1h[base + j] = hi;
      W1l[base + j] = f2b(v - b2f(hi));
    }
  } else if (b < 24) {                           // --- prepW2 (2048 frags)
    int g = (b - 16) * 256 + t;
    int l = g & 63, tt = (g >> 6) & 3, kc = (g >> 8) & 7;
    int n = tt * 16 + (l & 15);
    int kbase = kc * 32 + (l >> 4) * 8;
    size_t base = (((size_t)kc * 4 + tt) * 64 + l) * 8;
#pragma unroll
    for (int j = 0; j < 8; j++) {
      float v = W2[(size_t)(kbase + j) * 64 + n];
      unsigned short hi = f2b(v);
      W2h[base + j] = hi;
      W2l[base + j] = f2b(v - b2f(hi));
    }
  } else if (b < 28) {                           // --- vproj (1024 entries)
    int g = (b - 24) * 256 + t;
    int k = g >> 3, j = g & 7;
    int h = j & 3;
    const float* a = (j < 4) ? a_src1 : a_dst1;
    float s = 0.f;
    for (int c = 0; c < 64; c++) s += W1[(size_t)k * 256 + h * 64 + c] * a[h * 64 + c];
    va[k * 8 + j] = s;
  } else {                                       // --- ghist zero
    ghist[t] = 0;
  }
}

// ------------- layer-1 GEMM via MFMA: hact = relu(avgxb @ (W1h+W1l) + b1)
__global__ __launch_bounds__(256) void k_gh_mfma(const unsigned short* __restrict__ Ab,
                                                 const unsigned short* __restrict__ W1h,
                                                 const unsigned short* __restrict__ W1l,
                                                 const float* __restrict__ b1,
                                                 unsigned short* __restrict__ hact_hi,
                                                 unsigned short* __restrict__ hact_lo,
                                                 int M) {
  const int w = threadIdx.x >> 6, l = threadIdx.x & 63;
  const int h = blockIdx.z;
  const int rowA = blockIdx.x * 64 + w * 16 + (l & 15);
  const int rA = rowA < M ? rowA : M - 1;
  const int kg = l >> 4;
  const unsigned short* Aptr = Ab + (size_t)rA * 512 + h * 128 + kg * 8;
  f32x4 acc[4] = {{0.f, 0.f, 0.f, 0.f}, {0.f, 0.f, 0.f, 0.f},
                  {0.f, 0.f, 0.f, 0.f}, {0.f, 0.f, 0.f, 0.f}};
#pragma unroll
  for (int kc = 0; kc < 4; kc++) {
    bf16x8 a = *reinterpret_cast<const bf16x8*>(Aptr + kc * 32);
#pragma unroll
    for (int t = 0; t < 4; t++) {
      size_t base = ((((size_t)h * 4 + kc) * 4 + t) * 64 + l) * 8;
      bf16x8 bh = *reinterpret_cast<const bf16x8*>(W1h + base);
      bf16x8 bl = *reinterpret_cast<const bf16x8*>(W1l + base);
      acc[t] = __builtin_amdgcn_mfma_f32_16x16x32_bf16(a, bh, acc[t], 0, 0, 0);
      acc[t] = __builtin_amdgcn_mfma_f32_16x16x32_bf16(a, bl, acc[t], 0, 0, 0);
    }
  }
  const int orow0 = blockIdx.x * 64 + w * 16 + (l >> 4) * 4;
  const int col16 = l & 15;
#pragma unroll
  for (int t = 0; t < 4; t++) {
    int col = h * 64 + t * 16 + col16;
    float bb = b1[col];
#pragma unroll
    for (int r = 0; r < 4; r++) {
      int row = orow0 + r;
      if (row < M) {
        float v = fmaxf(acc[t][r] + bb, 0.f);
        unsigned short hi = f2b(v);
        hact_hi[(size_t)row * 256 + col] = hi;
        hact_lo[(size_t)row * 256 + col] = f2b(v - b2f(hi));
      }
    }
  }
}

// ------------- layer-2 GEMM via MFMA: h2b = (Ah+Al) @ (W2h+W2l), K=256
__global__ __launch_bounds__(256) void k_g2_mfma(const unsigned short* __restrict__ Ahi,
                                                 const unsigned short* __restrict__ Alo,
                                                 const unsigned short* __restrict__ W2h,
                                                 const unsigned short* __restrict__ W2l,
                                                 unsigned short* __restrict__ h2b,
                                                 int M) {
  const int w = threadIdx.x >> 6, l = threadIdx.x & 63;
  const int rowA = blockIdx.x * 64 + w * 16 + (l & 15);
  const int rA = rowA < M ? rowA : M - 1;
  const int kg = l >> 4;
  const unsigned short* Ah = Ahi + (size_t)rA * 256 + kg * 8;
  const unsigned short* Al = Alo + (size_t)rA * 256 + kg * 8;
  f32x4 acc[4] = {{0.f, 0.f, 0.f, 0.f}, {0.f, 0.f, 0.f, 0.f},
                  {0.f, 0.f, 0.f, 0.f}, {0.f, 0.f, 0.f, 0.f}};
#pragma unroll
  for (int kc = 0; kc < 8; kc++) {
    bf16x8 ah = *reinterpret_cast<const bf16x8*>(Ah + kc * 32);
    bf16x8 al = *reinterpret_cast<const bf16x8*>(Al + kc * 32);
#pragma unroll
    for (int t = 0; t < 4; t++) {
      size_t base = (((size_t)kc * 4 + t) * 64 + l) * 8;
      bf16x8 bh = *reinterpret_cast<const bf16x8*>(W2h + base);
      bf16x8 bl = *reinterpret_cast<const bf16x8*>(W2l + base);
      acc[t] = __builtin_amdgcn_mfma_f32_16x16x32_bf16(ah, bh, acc[t], 0, 0, 0);
      acc[t] = __builtin_amdgcn_mfma_f32_16x16x32_bf16(ah, bl, acc[t], 0, 0, 0);
      acc[t] = __builtin_amdgcn_mfma_f32_16x16x32_bf16(al, bh, acc[t], 0, 0, 0);
    }
  }
  const int orow0 = blockIdx.x * 64 + w * 16 + (l >> 4) * 4;
  const int col16 = l & 15;
#pragma unroll
  for (int t = 0; t < 4; t++) {
    int col = t * 16 + col16;
#pragma unroll
    for (int r = 0; r < 4; r++) {
      int row = orow0 + r;
      if (row < M) h2b[(size_t)row * 64 + col] = f2b(acc[t][r]);
    }
  }
}

// --- scores from x + fused bf16 cast + (tail blocks) coarse histogram -------
__global__ __launch_bounds__(256) void k_sxh(const float* __restrict__ x,
                                             const float* __restrict__ va,
                                             float* __restrict__ s_src,
                                             float* __restrict__ s_dst,
                                             unsigned short* __restrict__ xb,
                                             int N, int nsx,
                                             const int* __restrict__ ei,
                                             int E, int Etot,
                                             int* __restrict__ ghist) {
  __shared__ int lh[256];
  if (blockIdx.x >= nsx) {                 // ---- histogram part
    int t = threadIdx.x;
    lh[t] = 0;
    __syncthreads();
    int base = ((blockIdx.x - nsx) * 256 + t) * 8;
#pragma unroll
    for (int j = 0; j < 8; j++) {
      int e = base + j;
      if (e < Etot) {
        int dst = (e < E) ? ei[E + e] : (e - E);
        atomicAdd(&lh[dst >> 8], 1);
      }
    }
    __syncthreads();
    if (lh[t]) atomicAdd(&ghist[t], lh[t]);
    return;
  }
  int n = blockIdx.x * 4 + (threadIdx.x >> 6);
  if (n >= N) return;
  int lane = threadIdx.x & 63;
  float x0 = x[(size_t)n * 128 + lane];
  float x1 = x[(size_t)n * 128 + 64 + lane];
  xb[(size_t)n * 128 + lane] = f2b(x0);
  xb[(size_t)n * 128 + 64 + lane] = f2b(x1);
  float4 vs0 = *reinterpret_cast<const float4*>(va + lane * 8);
  float4 vd0 = *reinterpret_cast<const float4*>(va + lane * 8 + 4);
  float4 vs1 = *reinterpret_cast<const float4*>(va + (lane + 64) * 8);
  float4 vd1 = *reinterpret_cast<const float4*>(va + (lane + 64) * 8 + 4);
  float rs0 = x0 * vs0.x + x1 * vs1.x, rs1 = x0 * vs0.y + x1 * vs1.y;
  float rs2 = x0 * vs0.z + x1 * vs1.z, rs3 = x0 * vs0.w + x1 * vs1.w;
  float rd0 = x0 * vd0.x + x1 * vd1.x, rd1 = x0 * vd0.y + x1 * vd1.y;
  float rd2 = x0 * vd0.z + x1 * vd1.z, rd3 = x0 * vd0.w + x1 * vd1.w;
#pragma unroll
  for (int off = 32; off; off >>= 1) {
    rs0 += __shfl_xor(rs0, off, 64); rs1 += __shfl_xor(rs1, off, 64);
    rs2 += __shfl_xor(rs2, off, 64); rs3 += __shfl_xor(rs3, off, 64);
    rd0 += __shfl_xor(rd0, off, 64); rd1 += __shfl_xor(rd1, off, 64);
    rd2 += __shfl_xor(rd2, off, 64); rd3 += __shfl_xor(rd3, off, 64);
  }
  if (lane == 0) {
    float4 ss = {rs0, rs1, rs2, rs3};
    float4 dd = {rd0, rd1, rd2, rd3};
    *reinterpret_cast<float4*>(s_src + (size_t)n * 4) = ss;
    *reinterpret_cast<float4*>(s_dst + (size_t)n * 4) = dd;
  }
}

// ------------------------------------------- scores for layer 2 (bf16 input)
__global__ __launch_bounds__(256) void k_scores2(const unsigned short* __restrict__ h2b,
                                                 const float* __restrict__ a_src,
                                                 const float* __restrict__ a_dst,
                                                 float* __restrict__ s_src,
                                                 float* __restrict__ s_dst,
                                                 int N) {
  int n = blockIdx.x * 4 + (threadIdx.x >> 6);
  if (n >= N) return;
  int lane = threadIdx.x & 63;
  float hv = b2f(h2b[(size_t)n * 64 + lane]);
  float sv = hv * a_src[lane];
  float dv = hv * a_dst[lane];
#pragma unroll
  for (int off = 32; off; off >>= 1) {
    sv += __shfl_xor(sv, off, 64);
    dv += __shfl_xor(dv, off, 64);
  }
  if (lane == 0) {
    s_src[n] = sv;
    s_dst[n] = dv;
  }
}

// =================== MSD bucket sort CSR build ==============================
__global__ __launch_bounds__(256) void k_scan196(const int* __restrict__ ghist,
                                                 int* __restrict__ bstart,
                                                 int* __restrict__ gcur,
                                                 int nbuck, int Etot) {
  __shared__ int ws[4];
  int t = threadIdx.x;
  int lane = t & 63, wid = t >> 6;
  int v = (t < nbuck) ? ghist[t] : 0;
  int x = v;
#pragma unroll
  for (int off = 1; off < 64; off <<= 1) {
    int y = __shfl_up(x, off, 64);
    if (lane >= off) x += y;
  }
  if (lane == 63) ws[wid] = x;
  __syncthreads();
  if (t == 0) {
    int a0 = ws[0], a1 = ws[1], a2 = ws[2];
    ws[0] = 0; ws[1] = a0; ws[2] = a0 + a1; ws[3] = a0 + a1 + a2;
  }
  __syncthreads();
  int excl = x - v + ws[wid];
  if (t < nbuck) {
    bstart[t] = excl;
    gcur[t] = excl;
  }
  if (t == 0) bstart[nbuck] = Etot;
}

__global__ void k_scatterA(const int* __restrict__ ei, int E, int Etot,
                           int* __restrict__ gcur,
                           int* __restrict__ keys1,
                           int* __restrict__ vals1) {
  __shared__ int lh[256];
  int t = threadIdx.x;
  lh[t] = 0;
  __syncthreads();
  int base = (blockIdx.x * 256 + t) * 8;
  int dsts[8], srcs[8];
#pragma unroll
  for (int j = 0; j < 8; j++) {
    int e = base + j;
    if (e < Etot) {
      int d, s;
      if (e < E) { d = ei[E + e]; s = ei[e]; }
      else       { d = s = e - E; }
      dsts[j] = d; srcs[j] = s;
      atomicAdd(&lh[d >> 8], 1);
    } else dsts[j] = -1;
  }
  __syncthreads();
  {
    int c = lh[t];
    lh[t] = c ? atomicAdd(&gcur[t], c) : 0;   // reserve contiguous range
  }
  __syncthreads();
#pragma unroll
  for (int j = 0; j < 8; j++) {
    if (dsts[j] >= 0) {
      int pos = atomicAdd(&lh[dsts[j] >> 8], 1);  // LDS cursor -> global pos
      keys1[pos] = dsts[j];
      vals1[pos] = srcs[j];
    }
  }
}

__global__ __launch_bounds__(256) void k_sortB(const int* __restrict__ keys1,
                                               const int* __restrict__ vals1,
                                               const int* __restrict__ bstart,
                                               int* __restrict__ src_sorted,
                                               int* __restrict__ row_ptr,
                                               int N, int Etot) {
  __shared__ int lh[256];
  __shared__ int ws[4];
  int b = blockIdx.x;
  int t = threadIdx.x;
  int lane = t & 63, wid = t >> 6;
  int s = bstart[b], e2 = bstart[b + 1];
  lh[t] = 0;
  __syncthreads();
  for (int p = s + t; p < e2; p += 256)
    atomicAdd(&lh[keys1[p] & 255], 1);
  __syncthreads();
  int v = lh[t];
  int x = v;
#pragma unroll
  for (int off = 1; off < 64; off <<= 1) {
    int y = __shfl_up(x, off, 64);
    if (lane >= off) x += y;
  }
  if (lane == 63) ws[wid] = x;
  __syncthreads();
  if (t == 0) {
    int a0 = ws[0], a1 = ws[1], a2 = ws[2];
    ws[0] = 0; ws[1] = a0; ws[2] = a0 + a1; ws[3] = a0 + a1 + a2;
  }
  __syncthreads();
  int excl = x - v + ws[wid];
  int dst = (b << 8) + t;
  if (dst < N) row_ptr[dst] = s + excl;
  __syncthreads();
  lh[t] = s + excl;        // reuse as cursor
  __syncthreads();
  for (int p = s + t; p < e2; p += 256) {
    int k = keys1[p] & 255;
    int pos = atomicAdd(&lh[k], 1);
    src_sorted[pos] = vals1[p];
  }
  if (b == 0 && t == 0) row_ptr[N] = Etot;
}

// ============ FUSED layer-1 edge-weights + aggregation (wave-local) =========
// Per 64-edge chunk: phase A (lane=edge) computes w -> LDS + wsum partials;
// phase B (lane=channel-pair) broadcast-reads (src,w) and aggregates.
// Numerics identical to round-10 proven path: acc = sum(w*x); /(wsum+1e-16).
__global__ __launch_bounds__(256) void k_agg1f(const unsigned short* __restrict__ xb,
                                               const int* __restrict__ row_ptr,
                                               const int* __restrict__ src_sorted,
                                               const float* __restrict__ s_src,
                                               const float* __restrict__ s_dst,
                                               unsigned short* __restrict__ avgxb,
                                               int N) {
  __shared__ int    lsrc[4][64];
  __shared__ __align__(16) float4 lw[4][64];
  const int wv = threadIdx.x >> 6;
  const int n = blockIdx.x * 4 + wv;
  if (n >= N) return;
  const int lane = threadIdx.x & 63;
  float4 sd = *reinterpret_cast<const float4*>(s_dst + (size_t)n * 4);
  int beg = row_ptr[n], end = row_ptr[n + 1];
  float acc[4][2] = {};
  float ws0 = 0.f, ws1 = 0.f, ws2 = 0.f, ws3 = 0.f;

  for (int base = beg; base < end; base += 64) {
    int cnt = end - base;
    if (cnt > 64) cnt = 64;
    // ---- phase A: lane = edge
    if (lane < cnt) {
      int s = src_sorted[base + lane];
      float4 ss = *reinterpret_cast<const float4*>(s_src + (size_t)s * 4);
      float4 w;
      w.x = leaky_exp(ss.x + sd.x);
      w.y = leaky_exp(ss.y + sd.y);
      w.z = leaky_exp(ss.z + sd.z);
      w.w = leaky_exp(ss.w + sd.w);
      lsrc[wv][lane] = s;
      lw[wv][lane] = w;
      ws0 += w.x; ws1 += w.y; ws2 += w.z; ws3 += w.w;
    }
    __asm__ volatile("s_waitcnt lgkmcnt(0)" ::: "memory");
    // ---- phase B: lane = channel pair; broadcast (src,w) from LDS
    int j = 0;
    for (; j + 8 <= cnt; j += 8) {
      int s[8];
      float4 w[8];
      unsigned int pk[8];
#pragma unroll
      for (int q = 0; q < 8; q++) s[q] = lsrc[wv][j + q];
#pragma unroll
      for (int q = 0; q < 8; q++) w[q] = lw[wv][j + q];
#pragma unroll
      for (int q = 0; q < 8; q++)
        pk[q] = *reinterpret_cast<const unsigned int*>(xb + (size_t)s[q] * 128 + lane * 2);
#pragma unroll
      for (int q = 0; q < 8; q++) {
        float x0 = __uint_as_float(pk[q] << 16);
        float x1 = __uint_as_float(pk[q] & 0xFFFF0000u);
        acc[0][0] = fmaf(w[q].x, x0, acc[0][0]); acc[0][1] = fmaf(w[q].x, x1, acc[0][1]);
        acc[1][0] = fmaf(w[q].y, x0, acc[1][0]); acc[1][1] = fmaf(w[q].y, x1, acc[1][1]);
        acc[2][0] = fmaf(w[q].z, x0, acc[2][0]); acc[2][1] = fmaf(w[q].z, x1, acc[2][1]);
        acc[3][0] = fmaf(w[q].w, x0, acc[3][0]); acc[3][1] = fmaf(w[q].w, x1, acc[3][1]);
      }
    }
    for (; j < cnt; j++) {
      int s = lsrc[wv][j];
      float4 w = lw[wv][j];
      unsigned int pk = *reinterpret_cast<const unsigned int*>(xb + (size_t)s * 128 + lane * 2);
      float x0 = __uint_as_float(pk << 16);
      float x1 = __uint_as_float(pk & 0xFFFF0000u);
      acc[0][0] = fmaf(w.x, x0, acc[0][0]); acc[0][1] = fmaf(w.x, x1, acc[0][1]);
      acc[1][0] = fmaf(w.y, x0, acc[1][0]); acc[1][1] = fmaf(w.y, x1, acc[1][1]);
      acc[2][0] = fmaf(w.z, x0, acc[2][0]); acc[2][1] = fmaf(w.z, x1, acc[2][1]);
      acc[3][0] = fmaf(w.w, x0, acc[3][0]); acc[3][1] = fmaf(w.w, x1, acc[3][1]);
    }
  }
  // wave-reduce wsum (edge-parallel partials)
#pragma unroll
  for (int off = 32; off; off >>= 1) {
    ws0 += __shfl_xor(ws0, off, 64); ws1 += __shfl_xor(ws1, off, 64);
    ws2 += __shfl_xor(ws2, off, 64); ws3 += __shfl_xor(ws3, off, 64);
  }
  float inv[4] = {1.f / (ws0 + 1e-16f), 1.f / (ws1 + 1e-16f),
                  1.f / (ws2 + 1e-16f), 1.f / (ws3 + 1e-16f)};
#pragma unroll
  for (int h = 0; h < 4; h++) {
    unsigned int pk = ((unsigned int)f2b(acc[h][1] * inv[h]) << 16) | f2b(acc[h][0] * inv[h]);
    *reinterpret_cast<unsigned int*>(avgxb + (size_t)n * 512 + h * 128 + lane * 2) = pk;
  }
}

// ======== FUSED layer-2 edge-weights + aggregation + relu + out head ========
__global__ __launch_bounds__(256) void k_agg2f(const unsigned short* __restrict__ h2b,
                                               const int* __restrict__ row_ptr,
                                               const int* __restrict__ src_sorted,
                                               const float* __restrict__ s2s,
                                               const float* __restrict__ s2d,
                                               const float* __restrict__ bias,
                                               const float* __restrict__ Wout,
                                               const float* __restrict__ bout,
                                               float* __restrict__ logits, int N) {
  __shared__ int   lsrc[4][64];
  __shared__ float lw[4][64];
  const int wv = threadIdx.x >> 6;
  const int n = blockIdx.x * 4 + wv;
  if (n >= N) return;
  const int lane = threadIdx.x & 63;
  float sdn = s2d[n];
  int beg = row_ptr[n], end = row_ptr[n + 1];
  float acc = 0.f, wsp = 0.f;

  for (int base = beg; base < end; base += 64) {
    int cnt = end - base;
    if (cnt > 64) cnt = 64;
    if (lane < cnt) {
      int s = src_sorted[base + lane];
      float w = leaky_exp(s2s[s] + sdn);
      lsrc[wv][lane] = s;
      lw[wv][lane] = w;
      wsp += w;
    }
    __asm__ volatile("s_waitcnt lgkmcnt(0)" ::: "memory");
    int j = 0;
    for (; j + 8 <= cnt; j += 8) {
      int s[8];
      float w[8];
      unsigned short hv[8];
#pragma unroll
      for (int q = 0; q < 8; q++) s[q] = lsrc[wv][j + q];
#pragma unroll
      for (int q = 0; q < 8; q++) w[q] = lw[wv][j + q];
#pragma unroll
      for (int q = 0; q < 8; q++) hv[q] = h2b[(size_t)s[q] * 64 + lane];
#pragma unroll
      for (int q = 0; q < 8; q++) acc = fmaf(w[q], b2f(hv[q]), acc);
    }
    for (; j < cnt; j++) {
      acc = fmaf(lw[wv][j], b2f(h2b[(size_t)lsrc[wv][j] * 64 + lane]), acc);
    }
  }
#pragma unroll
  for (int off = 32; off; off >>= 1) wsp += __shfl_xor(wsp, off, 64);
  float o = fmaxf(acc / (wsp + 1e-16f) + bias[lane], 0.f);
  float v = o * Wout[lane];
#pragma unroll
  for (int off = 32; off; off >>= 1) v += __shfl_xor(v, off, 64);
  if (lane == 0) logits[n] = v + bout[0];
}

extern "C" void kernel_launch(void* const* d_in, const int* in_sizes, int n_in,
                              void* d_out, int out_size, void* d_ws, size_t ws_size,
                              hipStream_t stream) {
  const float* x      = (const float*)d_in[0];
  const int*   ei     = (const int*)d_in[1];
  const float* W1     = (const float*)d_in[2];
  const float* a_src1 = (const float*)d_in[3];
  const float* a_dst1 = (const float*)d_in[4];
  const float* b1     = (const float*)d_in[5];
  const float* W2     = (const float*)d_in[6];
  const float* a_src2 = (const float*)d_in[7];
  const float* a_dst2 = (const float*)d_in[8];
  const float* b2     = (const float*)d_in[9];
  const float* Wout   = (const float*)d_in[10];
  const float* bout   = (const float*)d_in[11];
  float* logits = (float*)d_out;

  const int HC1  = in_sizes[5];           // 256
  const int F_IN = in_sizes[2] / HC1;     // 128
  const int N    = in_sizes[0] / F_IN;    // 50000
  const int E    = in_sizes[1] / 2;       // 1.6M
  const int Etot = E + N;
  const int NBUCK = (N + 255) >> 8;       // 196 (<=256 supported)

  char* w = (char*)d_ws;
  auto alloc = [&](size_t bytes) {
    char* p = w;
    w += (bytes + 255) & ~(size_t)255;
    return p;
  };
  // region A: xb (bf16 x); dead after k_agg1f
  char* regA = alloc((size_t)N * 128 * sizeof(unsigned short));  // 12.8 MB
  unsigned short* xb = (unsigned short*)regA;
  // region B: avgxb (bf16); dead after k_gh_mfma -> h2b at offset 0
  char* regB = alloc((size_t)N * 512 * sizeof(unsigned short));  // 51.2 MB
  unsigned short* avgxb = (unsigned short*)regB;
  unsigned short* h2b = (unsigned short*)regB;
  // region C (51.2 MB), time-multiplexed:
  //   phase 1: keys1 (6.6 MB) + vals1 (6.6 MB)      [sort, dead after k_sortB]
  //   phase 2: hact_hi (25.6 MB) + hact_lo (25.6 MB)
  char* regC = alloc((size_t)N * 256 * 4);                       // 51.2 MB
  int* keys1 = (int*)regC;
  int* vals1 = (int*)(regC + (size_t)Etot * 4 + 256);
  unsigned short* hact_hi = (unsigned short*)regC;
  unsigned short* hact_lo = (unsigned short*)(regC + (size_t)N * 256 * sizeof(unsigned short));
  float* s_src1  = (float*)alloc((size_t)N * 4 * 4);
  float* s_dst1  = (float*)alloc((size_t)N * 4 * 4);
  float* s2_src  = (float*)alloc((size_t)N * 4);
  float* s2_dst  = (float*)alloc((size_t)N * 4);
  float* va      = (float*)alloc(128 * 8 * 4);
  unsigned short* W1h = (unsigned short*)alloc(4096 * 8 * 2);    // 64 KB
  unsigned short* W1l = (unsigned short*)alloc(4096 * 8 * 2);
  unsigned short* W2h = (unsigned short*)alloc(2048 * 8 * 2);    // 32 KB
  unsigned short* W2l = (unsigned short*)alloc(2048 * 8 * 2);
  int* row_ptr   = (int*)alloc((size_t)(N + 1) * 4);
  int* src_sorted= (int*)alloc((size_t)Etot * 4);
  int* ghist     = (int*)alloc(256 * 4);
  int* bstart    = (int*)alloc(260 * 4);
  int* gcur      = (int*)alloc(256 * 4);

  // ---- prep: W hi/lo swizzles + vproj + ghist zero ----
  k_prep<<<29, 256, 0, stream>>>(W1, W2, a_src1, a_dst1, W1h, W1l, W2h, W2l,
                                 va, ghist);

  // ---- scores_x (+cast) fused with coarse histogram ----
  const int nsx = (N + 3) / 4;
  const int gsort = (Etot + 2047) / 2048;
  k_sxh<<<nsx + gsort, 256, 0, stream>>>(x, va, s_src1, s_dst1, xb, N, nsx,
                                         ei, E, Etot, ghist);

  // ---- CSR build via MSD bucket sort ----
  k_scan196<<<1, 256, 0, stream>>>(ghist, bstart, gcur, NBUCK, Etot);
  k_scatterA<<<gsort, 256, 0, stream>>>(ei, E, Etot, gcur, keys1, vals1);
  k_sortB<<<NBUCK, 256, 0, stream>>>(keys1, vals1, bstart, src_sorted, row_ptr, N, Etot);

  // ---- layer 1 (h1 never materialized; weights computed in-kernel) ----
  k_agg1f<<<(N + 3) / 4, 256, 0, stream>>>(xb, row_ptr, src_sorted,
                                           s_src1, s_dst1, avgxb, N);
  dim3 gh((N + 63) / 64, 1, 4);
  k_gh_mfma<<<gh, 256, 0, stream>>>(avgxb, W1h, W1l, b1, hact_hi, hact_lo, N);

  // ---- layer 2 ----
  k_g2_mfma<<<(N + 63) / 64, 256, 0, stream>>>(hact_hi, hact_lo, W2h, W2l, h2b, N);
  k_scores2<<<(N + 3) / 4, 256, 0, stream>>>(h2b, a_src2, a_dst2, s2_src, s2_dst, N);
  k_agg2f<<<(N + 3) / 4, 256, 0, stream>>>(h2b, row_ptr, src_sorted,
                                           s2_src, s2_dst, b2, Wout, bout,
                                           logits, N);
}